// Round 5
// baseline (287.380 us; speedup 1.0000x reference)
//
#include <hip/hip_runtime.h>

// MultiHeadAttention B=2,S=2048,E=512,H=8,dh=64 — bf16 MFMA, split-K flash.
// Head mapping (VERIFIED r3): head h of batch b = contiguous [2048][64] span at
// flat offset (b*8+h)*S*64 of the projected [4096][512] tensor.
// R5: (1) cvt kernel: q/k/v/W -> bf16 once (proj traffic halves, staging has
// zero pack VALU); mask -> bf16 stored in d_out (exact for zero mask; d_out is
// overwritten by combine at the end). (2) attn prefetches the mask tile one
// kt-iteration ahead into registers (removes in-loop L3 latency stall).
// Scale quirk: 1/sqrt(s_k) = 1/sqrt(2048).

#define SEQ 2048
#define EMB 512
#define DH  64
#define MROWS 4096
#define NROWS 32768   // 16 heads * 2048 rows of 64

typedef float  v4f __attribute__((ext_vector_type(4)));
typedef short  v8s __attribute__((ext_vector_type(8)));

static __device__ __forceinline__ unsigned int f2bf(float f) {
    unsigned int u = __float_as_uint(f);
    u += 0x7fffu + ((u >> 16) & 1u);       // RNE
    return u >> 16;
}
static __device__ __forceinline__ unsigned int pack2(float a, float b) {
    return f2bf(a) | (f2bf(b) << 16);
}

// ---------------------------------------------------------------------------
// Bulk fp32 -> bf16 conversion. Units of 4 floats -> uint2.
// Segments (units): q,k,v 3x524288 | Wq,Wk,Wv 3x65536 | mask 1048576.
// ---------------------------------------------------------------------------
__global__ __launch_bounds__(256) void cvt_kernel(
    const float* __restrict__ q, const float* __restrict__ k, const float* __restrict__ v,
    const float* __restrict__ Wq, const float* __restrict__ Wk, const float* __restrict__ Wv,
    const float* __restrict__ mask,
    unsigned int* __restrict__ qc, unsigned int* __restrict__ kc, unsigned int* __restrict__ vc,
    unsigned int* __restrict__ Wc, unsigned int* __restrict__ maskc)
{
    const int NU = 2818048;
    for (int u = blockIdx.x * 256 + threadIdx.x; u < NU; u += gridDim.x * 256) {
        const float* s; unsigned int* d; int r;
        if (u < 1572864) {
            int which = u >> 19; r = u & 524287;
            s = (which == 0) ? q : (which == 1) ? k : v;
            d = (which == 0) ? qc : (which == 1) ? kc : vc;
        } else if (u < 1769472) {
            int t = u - 1572864; int which = t >> 16; r = t & 65535;
            s = (which == 0) ? Wq : (which == 1) ? Wk : Wv;
            d = Wc + which * 131072;
        } else {
            r = u - 1769472; s = mask; d = maskc;
        }
        float4 f = *(const float4*)&s[(size_t)r * 4];
        uint2 o = { pack2(f.x, f.y), pack2(f.z, f.w) };
        *(uint2*)&d[(size_t)r * 2] = o;
    }
}

// ---------------------------------------------------------------------------
// Projection (bf16 in, bf16 out): C[m][n] = sum_k A[m][k]*W[n][k] + bias[n].
// A [4096][512] bf16, W [512][512] bf16. 128(m) x 128(n) tile, BK=64.
// Staging = pure uint4 ld/st (no conversion VALU). LDS layout/frag math
// identical to the r4-verified kernel.
// ---------------------------------------------------------------------------
__global__ __launch_bounds__(256, 2) void proj_kernel(
    const unsigned short* __restrict__ qc, const unsigned short* __restrict__ kc,
    const unsigned short* __restrict__ vc, const unsigned short* __restrict__ Wc,
    const float* __restrict__ bq, const float* __restrict__ bk, const float* __restrict__ bv,
    unsigned short* __restrict__ Qbf, unsigned short* __restrict__ Kbf,
    unsigned short* __restrict__ Vbf)
{
    __shared__ __align__(16) char smem[36864];   // As 128x144 | Ws 128x144
    char* As = smem;
    char* Ws = smem + 18432;

    const int z = blockIdx.z;
    const unsigned short* A  = (z == 0) ? qc : (z == 1) ? kc : vc;
    const unsigned short* Wz = Wc + (size_t)z * 262144;
    const float* bias        = (z == 0) ? bq : (z == 1) ? bk : bv;
    unsigned short* Cg       = (z == 0) ? Qbf : (z == 1) ? Kbf : Vbf;

    const int tid  = threadIdx.x;
    const int w    = tid >> 6;
    const int lane = tid & 63;
    const int qd   = lane >> 4;
    const int n    = lane & 15;
    const int nb = blockIdx.x;      // 0..3
    const int mb = blockIdx.y;      // 0..31
    const int m0 = mb * 128, n0 = nb * 128;

    const int rA = tid & 127, hA = tid >> 7;   // row, half(32 elems = 64B)

    uint4 areg[4], wreg[4];
#pragma unroll
    for (int i = 0; i < 4; ++i) {
        areg[i] = *(const uint4*)&A [(size_t)(m0 + rA) * EMB + hA * 32 + i * 8];
        wreg[i] = *(const uint4*)&Wz[(size_t)(n0 + rA) * EMB + hA * 32 + i * 8];
    }

    v4f acc[2][8];
#pragma unroll
    for (int g = 0; g < 2; ++g)
#pragma unroll
        for (int cb = 0; cb < 8; ++cb) acc[g][cb] = (v4f)0.f;

#pragma unroll 1
    for (int kt = 0; kt < 8; ++kt) {
        __syncthreads();
#pragma unroll
        for (int i = 0; i < 4; ++i) {
            *(uint4*)&As[rA * 144 + hA * 64 + i * 16] = areg[i];
            *(uint4*)&Ws[rA * 144 + hA * 64 + i * 16] = wreg[i];
        }
        __syncthreads();

        if (kt + 1 < 8) {
#pragma unroll
            for (int i = 0; i < 4; ++i) {
                areg[i] = *(const uint4*)&A [(size_t)(m0 + rA) * EMB + (kt+1) * 64 + hA * 32 + i * 8];
                wreg[i] = *(const uint4*)&Wz[(size_t)(n0 + rA) * EMB + (kt+1) * 64 + hA * 32 + i * 8];
            }
        }

#pragma unroll
        for (int ks = 0; ks < 2; ++ks) {
            v8s af[2];
#pragma unroll
            for (int g = 0; g < 2; ++g)
                af[g] = *(const v8s*)&As[(w * 32 + g * 16 + n) * 144 + ks * 64 + qd * 16];
#pragma unroll
            for (int cb = 0; cb < 8; ++cb) {
                v8s bfr = *(const v8s*)&Ws[(cb * 16 + n) * 144 + ks * 64 + qd * 16];
#pragma unroll
                for (int g = 0; g < 2; ++g)
                    acc[g][cb] = __builtin_amdgcn_mfma_f32_16x16x32_bf16(af[g], bfr, acc[g][cb], 0, 0, 0);
            }
        }
    }

    float bb[8];
#pragma unroll
    for (int cb = 0; cb < 8; ++cb) bb[cb] = bias[n0 + cb * 16 + n];
#pragma unroll
    for (int g = 0; g < 2; ++g)
#pragma unroll
        for (int cb = 0; cb < 8; ++cb)
#pragma unroll
            for (int r = 0; r < 4; ++r) acc[g][cb][r] += bb[cb];

    __syncthreads();
    // bounce: Ct[128 rows][136 shorts pitch (272B)], then coalesced uint4 stores
    short* Ct = (short*)smem;
#pragma unroll
    for (int g = 0; g < 2; ++g)
#pragma unroll
        for (int cb = 0; cb < 8; ++cb)
#pragma unroll
            for (int r = 0; r < 4; ++r)
                Ct[(w * 32 + g * 16 + qd * 4 + r) * 136 + cb * 16 + n] =
                    (short)f2bf(acc[g][cb][r]);
    __syncthreads();
    const int rr = tid >> 1, hh = tid & 1;
#pragma unroll
    for (int i = 0; i < 8; ++i) {
        uint4 t4 = *(const uint4*)&smem[rr * 272 + hh * 128 + i * 16];
        *(uint4*)&Cg[(size_t)(m0 + rr) * EMB + n0 + hh * 64 + i * 8] = t4;
    }
}

// ---------------------------------------------------------------------------
// V transpose per head: contiguous [2048][64] head block -> VtG[bh][64][2048].
// ---------------------------------------------------------------------------
__global__ __launch_bounds__(256) void vtrans_kernel(
    const unsigned short* __restrict__ Vbf, unsigned short* __restrict__ VtG)
{
    __shared__ unsigned short T[64 * 136];
    const int bh = blockIdx.x, st = blockIdx.y;
    const int tid = threadIdx.x;
    const unsigned short* Vh = Vbf + (size_t)bh * (SEQ * DH) + (size_t)st * 128 * DH;
#pragma unroll
    for (int it = 0; it < 4; ++it) {
        int c = tid + it * 256;
        int s_l = c >> 3, ch = c & 7;
        uint4 t4 = *(const uint4*)&Vh[(size_t)s_l * DH + ch * 8];
        const unsigned short* e = (const unsigned short*)&t4;
#pragma unroll
        for (int j = 0; j < 8; ++j)
            T[(ch * 8 + j) * 136 + s_l] = e[j];
    }
    __syncthreads();
    const int d = tid >> 2, sq = tid & 3;
    unsigned short* Od = VtG + (size_t)bh * (DH * SEQ) + (size_t)d * SEQ + st * 128;
#pragma unroll
    for (int i = 0; i < 4; ++i) {
        uint4 t4 = *(const uint4*)&T[d * 136 + sq * 32 + i * 8];
        *(uint4*)&Od[sq * 32 + i * 8] = t4;
    }
}

// ---------------------------------------------------------------------------
// Flash attention, bf16 MFMA, transposed scores, split-K.
// SPLITS>1: bf16 mask (maskc) prefetched one kt ahead; writes Opart + (m,l).
// SPLITS==1: fallback, fp32 mask from d_in, writes d_out directly.
// ---------------------------------------------------------------------------
template <int SPLITS>
__global__ __launch_bounds__(256, 4) void attn_kernel(
    const unsigned short* __restrict__ Qbf, const unsigned short* __restrict__ Kbf,
    const unsigned short* __restrict__ VtG,
    const unsigned short* __restrict__ maskc, const float* __restrict__ maskf,
    float* __restrict__ Opart, float* __restrict__ ml, float* __restrict__ out)
{
    __shared__ __align__(16) char smem[36864];  // Ks 64x144 | Vts 64x144 | Ps 4x(32x144)
    char* Ks  = smem;
    char* Vts = smem + 9216;

    const int tid  = threadIdx.x;
    const int w    = tid >> 6;
    const int lane = tid & 63;
    const int qd   = lane >> 4;
    const int n    = lane & 15;
    char* Ps = smem + 18432 + w * 4608;

    const int bh = blockIdx.x;           // 0..15
    const int rb = blockIdx.y;           // 0..15
    const int kq = blockIdx.z;           // 0..SPLITS-1
    const int KT0 = kq * (32 / SPLITS), KT1 = KT0 + 32 / SPLITS;

    const unsigned short* Qh = Qbf + (size_t)bh * (SEQ * DH);
    const unsigned short* Kh = Kbf + (size_t)bh * (SEQ * DH);
    const unsigned short* Vth = VtG + (size_t)bh * (DH * SEQ);

    const float scale = 0.02209708691207961f;   // 1/sqrt(2048)

    v8s qf[2][2];
#pragma unroll
    for (int g = 0; g < 2; ++g) {
        const size_t qrow = (size_t)(rb * 128 + w * 32 + g * 16 + n);
#pragma unroll
        for (int ks = 0; ks < 2; ++ks)
            qf[g][ks] = *(const v8s*)&Qh[qrow * DH + ks * 32 + qd * 8];
    }

    const int sr = lane;
    uint4 kreg[2], vreg[2];
#pragma unroll
    for (int p = 0; p < 2; ++p) {
        kreg[p] = *(const uint4*)&Kh[(size_t)(KT0 * 64 + sr) * DH + (w * 2 + p) * 8];
        vreg[p] = *(const uint4*)&Vth[(size_t)sr * SEQ + KT0 * 64 + (w * 2 + p) * 8];
    }

    // bf16 mask prefetch state (split path)
    uint2 mcur[2][4], mnxt[2][4];
    if (SPLITS > 1) {
#pragma unroll
        for (int g = 0; g < 2; ++g) {
            const size_t mrow = (size_t)(rb * 128 + w * 32 + g * 16 + n);
#pragma unroll
            for (int cb = 0; cb < 4; ++cb)
                mcur[g][cb] = *(const uint2*)&maskc[mrow * SEQ + KT0 * 64 + cb * 16 + qd * 4];
        }
    }

    float m_[2] = { -1e30f, -1e30f }, l_[2] = { 0.f, 0.f };
    v4f oacc[2][4];
#pragma unroll
    for (int g = 0; g < 2; ++g)
#pragma unroll
        for (int cb = 0; cb < 4; ++cb) oacc[g][cb] = (v4f)0.f;

#pragma unroll 1
    for (int kt = KT0; kt < KT1; ++kt) {
        __syncthreads();
#pragma unroll
        for (int p = 0; p < 2; ++p) {
            *(uint4*)&Ks [sr * 144 + (w * 2 + p) * 16] = kreg[p];
            *(uint4*)&Vts[sr * 144 + (w * 2 + p) * 16] = vreg[p];
        }
        __syncthreads();

        if (kt + 1 < KT1) {
#pragma unroll
            for (int p = 0; p < 2; ++p) {
                kreg[p] = *(const uint4*)&Kh[(size_t)((kt + 1) * 64 + sr) * DH + (w * 2 + p) * 8];
                vreg[p] = *(const uint4*)&Vth[(size_t)sr * SEQ + (kt + 1) * 64 + (w * 2 + p) * 8];
            }
            if (SPLITS > 1) {
#pragma unroll
                for (int g = 0; g < 2; ++g) {
                    const size_t mrow = (size_t)(rb * 128 + w * 32 + g * 16 + n);
#pragma unroll
                    for (int cb = 0; cb < 4; ++cb)
                        mnxt[g][cb] = *(const uint2*)&maskc[mrow * SEQ + (kt + 1) * 64 + cb * 16 + qd * 4];
                }
            }
        }

        float4 mk[2][4];
        if (SPLITS == 1) {
#pragma unroll
            for (int g = 0; g < 2; ++g) {
                const size_t mrow = (size_t)(rb * 128 + w * 32 + g * 16 + n);
#pragma unroll
                for (int cb = 0; cb < 4; ++cb)
                    mk[g][cb] = *(const float4*)&maskf[mrow * SEQ + kt * 64 + cb * 16 + qd * 4];
            }
        }

        // ---- scores: S^T[s_k][qrow]
        v4f sacc[2][4];
#pragma unroll
        for (int g = 0; g < 2; ++g)
#pragma unroll
            for (int cb = 0; cb < 4; ++cb) sacc[g][cb] = (v4f)0.f;
#pragma unroll
        for (int ks = 0; ks < 2; ++ks)
#pragma unroll
            for (int cb = 0; cb < 4; ++cb) {
                v8s kf = *(const v8s*)&Ks[(cb * 16 + n) * 144 + ks * 64 + qd * 16];
#pragma unroll
                for (int g = 0; g < 2; ++g)
                    sacc[g][cb] = __builtin_amdgcn_mfma_f32_16x16x32_bf16(kf, qf[g][ks], sacc[g][cb], 0, 0, 0);
            }

        // ---- online softmax per qgroup (qrow = lane&15 -> per-lane scalars)
#pragma unroll
        for (int g = 0; g < 2; ++g) {
            float sv[4][4];
            float mx = -1e30f;
#pragma unroll
            for (int cb = 0; cb < 4; ++cb) {
                float mv[4];
                if (SPLITS > 1) {
                    uint2 mu = mcur[g][cb];
                    mv[0] = __uint_as_float(mu.x << 16);
                    mv[1] = __uint_as_float(mu.x & 0xFFFF0000u);
                    mv[2] = __uint_as_float(mu.y << 16);
                    mv[3] = __uint_as_float(mu.y & 0xFFFF0000u);
                } else {
                    mv[0] = mk[g][cb].x; mv[1] = mk[g][cb].y;
                    mv[2] = mk[g][cb].z; mv[3] = mk[g][cb].w;
                }
#pragma unroll
                for (int r = 0; r < 4; ++r) {
                    float s = fmaf(sacc[g][cb][r], scale, mv[r]);
                    sv[cb][r] = s;
                    mx = fmaxf(mx, s);
                }
            }
            mx = fmaxf(mx, __shfl_xor(mx, 16));
            mx = fmaxf(mx, __shfl_xor(mx, 32));
            const float mnew  = fmaxf(m_[g], mx);
            const float alpha = __expf(m_[g] - mnew);
            float rs = 0.f;
            float pv[4][4];
#pragma unroll
            for (int cb = 0; cb < 4; ++cb)
#pragma unroll
                for (int r = 0; r < 4; ++r) {
                    float e = __expf(sv[cb][r] - mnew);
                    pv[cb][r] = e;
                    rs += e;
                }
            rs += __shfl_xor(rs, 16);
            rs += __shfl_xor(rs, 32);
            l_[g] = l_[g] * alpha + rs;
            m_[g] = mnew;
#pragma unroll
            for (int cb = 0; cb < 4; ++cb) {
#pragma unroll
                for (int r = 0; r < 4; ++r) oacc[g][cb][r] *= alpha;
                uint2 pk = { pack2(pv[cb][0], pv[cb][1]), pack2(pv[cb][2], pv[cb][3]) };
                *(uint2*)&Ps[(g * 16 + n) * 144 + cb * 32 + qd * 8] = pk;
            }
        }

        if (SPLITS > 1 && kt + 1 < KT1) {
#pragma unroll
            for (int g = 0; g < 2; ++g)
#pragma unroll
                for (int cb = 0; cb < 4; ++cb) mcur[g][cb] = mnxt[g][cb];
        }

        // ---- PV: O^T[d][qrow] += Vt * P^T
#pragma unroll
        for (int ks = 0; ks < 2; ++ks) {
            v8s pf[2];
#pragma unroll
            for (int g = 0; g < 2; ++g)
                pf[g] = *(const v8s*)&Ps[(g * 16 + n) * 144 + ks * 64 + qd * 16];
#pragma unroll
            for (int cb = 0; cb < 4; ++cb) {
                v8s vf = *(const v8s*)&Vts[(cb * 16 + n) * 144 + ks * 64 + qd * 16];
#pragma unroll
                for (int g = 0; g < 2; ++g)
                    oacc[g][cb] = __builtin_amdgcn_mfma_f32_16x16x32_bf16(vf, pf[g], oacc[g][cb], 0, 0, 0);
            }
        }
    }

    // ---- epilogue
    if (SPLITS == 1) {
#pragma unroll
        for (int g = 0; g < 2; ++g) {
            const float inv = 1.0f / l_[g];
#pragma unroll
            for (int cb = 0; cb < 4; ++cb)
#pragma unroll
                for (int r = 0; r < 4; ++r) oacc[g][cb][r] *= inv;
        }
    } else {
        if (qd == 0) {
#pragma unroll
            for (int g = 0; g < 2; ++g) {
                const size_t row = (size_t)bh * SEQ + rb * 128 + w * 32 + g * 16 + n;
                ml[((size_t)kq * NROWS + row) * 2 + 0] = m_[g];
                ml[((size_t)kq * NROWS + row) * 2 + 1] = l_[g];
            }
        }
    }
    __syncthreads();
#pragma unroll
    for (int g = 0; g < 2; ++g)
#pragma unroll
        for (int cb = 0; cb < 4; ++cb)
            *(v4f*)&smem[(w * 32 + g * 16 + n) * 272 + cb * 64 + qd * 16] = oacc[g][cb];
    __syncthreads();
    const int r_l = tid >> 1, hf = tid & 1;
    float* dst = (SPLITS == 1)
        ? &out[((size_t)bh * SEQ + rb * 128 + r_l) * DH + hf * 32]
        : &Opart[((size_t)kq * NROWS + (size_t)bh * SEQ + rb * 128 + r_l) * DH + hf * 32];
#pragma unroll
    for (int i = 0; i < 8; ++i) {
        float4 t4 = *(const float4*)&smem[r_l * 272 + hf * 128 + i * 16];
        *(float4*)&dst[i * 4] = t4;
    }
}

// ---------------------------------------------------------------------------
// Combine split-K partials.
// ---------------------------------------------------------------------------
__global__ __launch_bounds__(256) void combine_kernel(
    const float* __restrict__ Opart, const float* __restrict__ ml,
    float* __restrict__ out, int splits)
{
    const int tid = threadIdx.x;
    const size_t row = (size_t)blockIdx.x * 16 + (tid >> 4);
    const int d4 = (tid & 15) * 4;
    float M = -1e30f;
    for (int s = 0; s < splits; ++s)
        M = fmaxf(M, ml[((size_t)s * NROWS + row) * 2]);
    float denom = 0.f;
    float4 o = make_float4(0.f, 0.f, 0.f, 0.f);
    for (int s = 0; s < splits; ++s) {
        const float ws = __expf(ml[((size_t)s * NROWS + row) * 2] - M);
        denom += ws * ml[((size_t)s * NROWS + row) * 2 + 1];
        float4 p = *(const float4*)&Opart[((size_t)s * NROWS + row) * DH + d4];
        o.x += ws * p.x; o.y += ws * p.y; o.z += ws * p.z; o.w += ws * p.w;
    }
    const float inv = 1.0f / denom;
    o.x *= inv; o.y *= inv; o.z *= inv; o.w *= inv;
    *(float4*)&out[row * DH + d4] = o;
}

extern "C" void kernel_launch(void* const* d_in, const int* in_sizes, int n_in,
                              void* d_out, int out_size, void* d_ws, size_t ws_size,
                              hipStream_t stream) {
    const float* q    = (const float*)d_in[0];
    const float* k    = (const float*)d_in[1];
    const float* v    = (const float*)d_in[2];
    const float* mask = (const float*)d_in[3];
    const float* Wq   = (const float*)d_in[4];
    const float* bq   = (const float*)d_in[5];
    const float* Wk   = (const float*)d_in[6];
    const float* bk   = (const float*)d_in[7];
    const float* Wv   = (const float*)d_in[8];
    const float* bv   = (const float*)d_in[9];

    char* ws = (char*)d_ws;
    const size_t MB = 1024 * 1024;
    // Long-lived:
    unsigned short* Qbf = (unsigned short*)(ws + 0);          // 4 MB
    unsigned short* Kbf = (unsigned short*)(ws + 4 * MB);     // 4 MB
    unsigned short* VtG = (unsigned short*)(ws + 8 * MB);     // 4 MB
    float*          mlp = (float*)(ws + 12 * MB);             // 1 MB
    float*          Opart = (float*)(ws + 13 * MB);           // 32 MB (attn phase)
    // Proj-phase overlays (dead before Opart is written):
    unsigned short* qc  = (unsigned short*)(ws + 13 * MB);    // 4 MB
    unsigned short* kc  = (unsigned short*)(ws + 17 * MB);    // 4 MB
    unsigned short* vc  = (unsigned short*)(ws + 21 * MB);    // 4 MB
    unsigned short* Wc  = (unsigned short*)(ws + 25 * MB);    // 1.5 MB
    unsigned short* Vbf = (unsigned short*)(ws + 27 * MB);    // 4 MB (dead after vtrans)

    const size_t need_split = 13 * MB + (size_t)4 * NROWS * DH * 4;  // 45 MB
    const bool do_split = ws_size >= need_split;

    // bf16 mask lives in d_out (exactly 8 MB); combine overwrites it at the end.
    unsigned short* maskc = (unsigned short*)d_out;

    cvt_kernel<<<1024, 256, 0, stream>>>(q, k, v, Wq, Wk, Wv, mask,
                                         (unsigned int*)qc, (unsigned int*)kc,
                                         (unsigned int*)vc, (unsigned int*)Wc,
                                         (unsigned int*)maskc);

    dim3 pgrid(EMB / 128, MROWS / 128, 3);   // 4 x 32 x 3 = 384 blocks
    proj_kernel<<<pgrid, 256, 0, stream>>>(qc, kc, vc, Wc, bq, bk, bv,
                                           Qbf, Kbf, Vbf);

    dim3 tgrid(16, SEQ / 128);
    vtrans_kernel<<<tgrid, 256, 0, stream>>>(Vbf, VtG);

    if (do_split) {
        dim3 agrid(16, SEQ / 128, 4);        // 1024 blocks -> 4 blocks/CU
        attn_kernel<4><<<agrid, 256, 0, stream>>>(Qbf, Kbf, VtG, maskc, mask,
                                                  Opart, mlp, (float*)d_out);
        combine_kernel<<<NROWS / 16, 256, 0, stream>>>(Opart, mlp, (float*)d_out, 4);
    } else {
        dim3 agrid(16, SEQ / 128, 1);
        attn_kernel<1><<<agrid, 256, 0, stream>>>(Qbf, Kbf, VtG, maskc, mask,
                                                  Opart, mlp, (float*)d_out);
    }
}

// Round 6
// 281.701 us; speedup vs baseline: 1.0202x; 1.0202x over previous
//
#include <hip/hip_runtime.h>

// MultiHeadAttention B=2,S=2048,E=512,H=8,dh=64 — bf16 MFMA, split-K flash.
// Head mapping (VERIFIED r3): head h of batch b = contiguous [2048][64] span at
// flat offset (b*8+h)*S*64 of the projected [4096][512] tensor.
// R6: revert r5's cvt/bf16-mask (regressed: d_out round-trip + extra pass made
// L3 hostile). Proj -> 64x128 tiles (768 blocks, 3/CU; r4's 384 was
// occupancy-bound at ~120us despite MFMA). Attn = r4 + fp32 mask register
// prefetch (loaded after softmax consumes current, hidden by PV+barrier).
// Scale quirk: 1/sqrt(s_k) = 1/sqrt(2048).

#define SEQ 2048
#define EMB 512
#define DH  64
#define MROWS 4096
#define NROWS 32768   // 16 heads * 2048 rows of 64

typedef float  v4f __attribute__((ext_vector_type(4)));
typedef short  v8s __attribute__((ext_vector_type(8)));

static __device__ __forceinline__ unsigned int f2bf(float f) {
    unsigned int u = __float_as_uint(f);
    u += 0x7fffu + ((u >> 16) & 1u);       // RNE
    return u >> 16;
}
static __device__ __forceinline__ unsigned int pack2(float a, float b) {
    return f2bf(a) | (f2bf(b) << 16);
}

// ---------------------------------------------------------------------------
// Projection: C[m][n] = sum_k A[m][k]*W[n][k] + bias[n], fp32 in, bf16 out.
// 64(m) x 128(n) tile, BK=64 -> grid (64 mb, 4 nb, 3 z) = 768 blocks, 3/CU.
// 4 waves, each one 16-row m-group x 8 cb. blockIdx.x=mb: consecutive blocks
// share the W n-strip (L2 reuse).
// ---------------------------------------------------------------------------
__global__ __launch_bounds__(256, 3) void proj_kernel(
    const float* __restrict__ q, const float* __restrict__ k, const float* __restrict__ v,
    const float* __restrict__ Wq, const float* __restrict__ bq,
    const float* __restrict__ Wk, const float* __restrict__ bk,
    const float* __restrict__ Wv, const float* __restrict__ bv,
    unsigned short* __restrict__ Qbf, unsigned short* __restrict__ Kbf,
    unsigned short* __restrict__ Vbf)
{
    __shared__ __align__(16) char smem[27648];   // As 64x144 (9216) | Ws 128x144 (18432)
    char* As = smem;
    char* Ws = smem + 9216;

    const int z = blockIdx.z;
    const float* A    = (z == 0) ? q  : (z == 1) ? k  : v;
    const float* W    = (z == 0) ? Wq : (z == 1) ? Wk : Wv;
    const float* bias = (z == 0) ? bq : (z == 1) ? bk : bv;
    unsigned short* Cg = (z == 0) ? Qbf : (z == 1) ? Kbf : Vbf;

    const int tid  = threadIdx.x;
    const int w    = tid >> 6;
    const int lane = tid & 63;
    const int qd   = lane >> 4;     // quad 0..3
    const int n    = lane & 15;
    const int mb = blockIdx.x;      // 0..63
    const int nb = blockIdx.y;      // 0..3
    const int m0 = mb * 64, n0 = nb * 128;

    const int rA = tid & 63,  qA = (tid >> 6) & 3;  // A: row, quarter (16 floats)
    const int rW = tid & 127, hW = tid >> 7;        // W: row, half (32 floats)

    float4 areg[4], wreg[8];
#pragma unroll
    for (int i = 0; i < 4; ++i)
        areg[i] = *(const float4*)&A[(size_t)(m0 + rA) * EMB + qA * 16 + i * 4];
#pragma unroll
    for (int i = 0; i < 8; ++i)
        wreg[i] = *(const float4*)&W[(size_t)(n0 + rW) * EMB + hW * 32 + i * 4];

    v4f acc[8];
#pragma unroll
    for (int cb = 0; cb < 8; ++cb) acc[cb] = (v4f)0.f;

#pragma unroll 1
    for (int kt = 0; kt < 8; ++kt) {
        __syncthreads();
#pragma unroll
        for (int i2 = 0; i2 < 2; ++i2) {
            uint4 pa = { pack2(areg[2*i2].x, areg[2*i2].y), pack2(areg[2*i2].z, areg[2*i2].w),
                         pack2(areg[2*i2+1].x, areg[2*i2+1].y), pack2(areg[2*i2+1].z, areg[2*i2+1].w) };
            *(uint4*)&As[rA * 144 + qA * 32 + i2 * 16] = pa;
        }
#pragma unroll
        for (int i2 = 0; i2 < 4; ++i2) {
            uint4 pw = { pack2(wreg[2*i2].x, wreg[2*i2].y), pack2(wreg[2*i2].z, wreg[2*i2].w),
                         pack2(wreg[2*i2+1].x, wreg[2*i2+1].y), pack2(wreg[2*i2+1].z, wreg[2*i2+1].w) };
            *(uint4*)&Ws[rW * 144 + hW * 64 + i2 * 16] = pw;
        }
        __syncthreads();

        if (kt + 1 < 8) {
#pragma unroll
            for (int i = 0; i < 4; ++i)
                areg[i] = *(const float4*)&A[(size_t)(m0 + rA) * EMB + (kt+1) * 64 + qA * 16 + i * 4];
#pragma unroll
            for (int i = 0; i < 8; ++i)
                wreg[i] = *(const float4*)&W[(size_t)(n0 + rW) * EMB + (kt+1) * 64 + hW * 32 + i * 4];
        }

#pragma unroll
        for (int ks = 0; ks < 2; ++ks) {
            v8s af = *(const v8s*)&As[(w * 16 + n) * 144 + ks * 64 + qd * 16];
#pragma unroll
            for (int cb = 0; cb < 8; ++cb) {
                v8s bfr = *(const v8s*)&Ws[(cb * 16 + n) * 144 + ks * 64 + qd * 16];
                acc[cb] = __builtin_amdgcn_mfma_f32_16x16x32_bf16(af, bfr, acc[cb], 0, 0, 0);
            }
        }
    }

    float bb[8];
#pragma unroll
    for (int cb = 0; cb < 8; ++cb) bb[cb] = bias[n0 + cb * 16 + n];
#pragma unroll
    for (int cb = 0; cb < 8; ++cb)
#pragma unroll
        for (int r = 0; r < 4; ++r) acc[cb][r] += bb[cb];

    __syncthreads();
    // bounce: Ct[64 rows][136 shorts pitch (272B)], then coalesced uint4 stores
    short* Ct = (short*)smem;
#pragma unroll
    for (int cb = 0; cb < 8; ++cb)
#pragma unroll
        for (int r = 0; r < 4; ++r)
            Ct[(w * 16 + qd * 4 + r) * 136 + cb * 16 + n] = (short)f2bf(acc[cb][r]);
    __syncthreads();
    const int rr = tid >> 2, q4 = tid & 3;
#pragma unroll
    for (int i = 0; i < 4; ++i) {
        uint4 t4 = *(const uint4*)&smem[rr * 272 + q4 * 64 + i * 16];
        *(uint4*)&Cg[(size_t)(m0 + rr) * EMB + n0 + q4 * 32 + i * 8] = t4;
    }
}

// ---------------------------------------------------------------------------
// V transpose per head: contiguous [2048][64] head block -> VtG[bh][64][2048].
// ---------------------------------------------------------------------------
__global__ __launch_bounds__(256) void vtrans_kernel(
    const unsigned short* __restrict__ Vbf, unsigned short* __restrict__ VtG)
{
    __shared__ unsigned short T[64 * 136];
    const int bh = blockIdx.x, st = blockIdx.y;
    const int tid = threadIdx.x;
    const unsigned short* Vh = Vbf + (size_t)bh * (SEQ * DH) + (size_t)st * 128 * DH;
#pragma unroll
    for (int it = 0; it < 4; ++it) {
        int c = tid + it * 256;
        int s_l = c >> 3, ch = c & 7;
        uint4 t4 = *(const uint4*)&Vh[(size_t)s_l * DH + ch * 8];
        const unsigned short* e = (const unsigned short*)&t4;
#pragma unroll
        for (int j = 0; j < 8; ++j)
            T[(ch * 8 + j) * 136 + s_l] = e[j];
    }
    __syncthreads();
    const int d = tid >> 2, sq = tid & 3;
    unsigned short* Od = VtG + (size_t)bh * (DH * SEQ) + (size_t)d * SEQ + st * 128;
#pragma unroll
    for (int i = 0; i < 4; ++i) {
        uint4 t4 = *(const uint4*)&T[d * 136 + sq * 32 + i * 8];
        *(uint4*)&Od[sq * 32 + i * 8] = t4;
    }
}

// ---------------------------------------------------------------------------
// Flash attention, bf16 MFMA, transposed scores, split-K (r4 structure).
// fp32 mask prefetched one kt ahead into registers (loaded after softmax
// consumes the current tile; PV + next barrier hide the latency).
// ---------------------------------------------------------------------------
template <int SPLITS>
__global__ __launch_bounds__(256, 4) void attn_kernel(
    const unsigned short* __restrict__ Qbf, const unsigned short* __restrict__ Kbf,
    const unsigned short* __restrict__ VtG, const float* __restrict__ mask,
    float* __restrict__ Opart, float* __restrict__ ml, float* __restrict__ out)
{
    __shared__ __align__(16) char smem[36864];  // Ks 64x144 | Vts 64x144 | Ps 4x(32x144)
    char* Ks  = smem;
    char* Vts = smem + 9216;

    const int tid  = threadIdx.x;
    const int w    = tid >> 6;
    const int lane = tid & 63;
    const int qd   = lane >> 4;
    const int n    = lane & 15;
    char* Ps = smem + 18432 + w * 4608;

    const int bh = blockIdx.x;           // 0..15
    const int rb = blockIdx.y;           // 0..15
    const int kq = blockIdx.z;           // 0..SPLITS-1
    const int KT0 = kq * (32 / SPLITS), KT1 = KT0 + 32 / SPLITS;

    const unsigned short* Qh = Qbf + (size_t)bh * (SEQ * DH);
    const unsigned short* Kh = Kbf + (size_t)bh * (SEQ * DH);
    const unsigned short* Vth = VtG + (size_t)bh * (DH * SEQ);

    const float scale = 0.02209708691207961f;   // 1/sqrt(2048)

    v8s qf[2][2];
#pragma unroll
    for (int g = 0; g < 2; ++g) {
        const size_t qrow = (size_t)(rb * 128 + w * 32 + g * 16 + n);
#pragma unroll
        for (int ks = 0; ks < 2; ++ks)
            qf[g][ks] = *(const v8s*)&Qh[qrow * DH + ks * 32 + qd * 8];
    }

    const int sr = lane;
    uint4 kreg[2], vreg[2];
#pragma unroll
    for (int p = 0; p < 2; ++p) {
        kreg[p] = *(const uint4*)&Kh[(size_t)(KT0 * 64 + sr) * DH + (w * 2 + p) * 8];
        vreg[p] = *(const uint4*)&Vth[(size_t)sr * SEQ + KT0 * 64 + (w * 2 + p) * 8];
    }

    // mask prefetch: mcur holds tile kt's mask values
    const size_t mrow0 = (size_t)(rb * 128 + w * 32 + n);
    float4 mcur[2][4];
#pragma unroll
    for (int g = 0; g < 2; ++g)
#pragma unroll
        for (int cb = 0; cb < 4; ++cb)
            mcur[g][cb] = *(const float4*)&mask[(mrow0 + g * 16) * SEQ + KT0 * 64 + cb * 16 + qd * 4];

    float m_[2] = { -1e30f, -1e30f }, l_[2] = { 0.f, 0.f };
    v4f oacc[2][4];
#pragma unroll
    for (int g = 0; g < 2; ++g)
#pragma unroll
        for (int cb = 0; cb < 4; ++cb) oacc[g][cb] = (v4f)0.f;

#pragma unroll 1
    for (int kt = KT0; kt < KT1; ++kt) {
        __syncthreads();
#pragma unroll
        for (int p = 0; p < 2; ++p) {
            *(uint4*)&Ks [sr * 144 + (w * 2 + p) * 16] = kreg[p];
            *(uint4*)&Vts[sr * 144 + (w * 2 + p) * 16] = vreg[p];
        }
        __syncthreads();

        if (kt + 1 < KT1) {
#pragma unroll
            for (int p = 0; p < 2; ++p) {
                kreg[p] = *(const uint4*)&Kh[(size_t)((kt + 1) * 64 + sr) * DH + (w * 2 + p) * 8];
                vreg[p] = *(const uint4*)&Vth[(size_t)sr * SEQ + (kt + 1) * 64 + (w * 2 + p) * 8];
            }
        }

        // ---- scores: S^T[s_k][qrow]
        v4f sacc[2][4];
#pragma unroll
        for (int g = 0; g < 2; ++g)
#pragma unroll
            for (int cb = 0; cb < 4; ++cb) sacc[g][cb] = (v4f)0.f;
#pragma unroll
        for (int ks = 0; ks < 2; ++ks)
#pragma unroll
            for (int cb = 0; cb < 4; ++cb) {
                v8s kf = *(const v8s*)&Ks[(cb * 16 + n) * 144 + ks * 64 + qd * 16];
#pragma unroll
                for (int g = 0; g < 2; ++g)
                    sacc[g][cb] = __builtin_amdgcn_mfma_f32_16x16x32_bf16(kf, qf[g][ks], sacc[g][cb], 0, 0, 0);
            }

        // ---- online softmax per qgroup (qrow = lane&15 -> per-lane scalars)
#pragma unroll
        for (int g = 0; g < 2; ++g) {
            float sv[4][4];
            float mx = -1e30f;
#pragma unroll
            for (int cb = 0; cb < 4; ++cb)
#pragma unroll
                for (int r = 0; r < 4; ++r) {
                    float s = fmaf(sacc[g][cb][r], scale, ((const float*)&mcur[g][cb])[r]);
                    sv[cb][r] = s;
                    mx = fmaxf(mx, s);
                }
            mx = fmaxf(mx, __shfl_xor(mx, 16));
            mx = fmaxf(mx, __shfl_xor(mx, 32));
            const float mnew  = fmaxf(m_[g], mx);
            const float alpha = __expf(m_[g] - mnew);
            float rs = 0.f;
            float pv[4][4];
#pragma unroll
            for (int cb = 0; cb < 4; ++cb)
#pragma unroll
                for (int r = 0; r < 4; ++r) {
                    float e = __expf(sv[cb][r] - mnew);
                    pv[cb][r] = e;
                    rs += e;
                }
            rs += __shfl_xor(rs, 16);
            rs += __shfl_xor(rs, 32);
            l_[g] = l_[g] * alpha + rs;
            m_[g] = mnew;
#pragma unroll
            for (int cb = 0; cb < 4; ++cb) {
#pragma unroll
                for (int r = 0; r < 4; ++r) oacc[g][cb][r] *= alpha;
                uint2 pk = { pack2(pv[cb][0], pv[cb][1]), pack2(pv[cb][2], pv[cb][3]) };
                *(uint2*)&Ps[(g * 16 + n) * 144 + cb * 32 + qd * 8] = pk;
            }
        }

        // ---- prefetch next mask tile (consumed next iteration; hidden by PV)
        if (kt + 1 < KT1) {
#pragma unroll
            for (int g = 0; g < 2; ++g)
#pragma unroll
                for (int cb = 0; cb < 4; ++cb)
                    mcur[g][cb] = *(const float4*)&mask[(mrow0 + g * 16) * SEQ + (kt + 1) * 64 + cb * 16 + qd * 4];
        }

        // ---- PV: O^T[d][qrow] += Vt * P^T
#pragma unroll
        for (int ks = 0; ks < 2; ++ks) {
            v8s pf[2];
#pragma unroll
            for (int g = 0; g < 2; ++g)
                pf[g] = *(const v8s*)&Ps[(g * 16 + n) * 144 + ks * 64 + qd * 16];
#pragma unroll
            for (int cb = 0; cb < 4; ++cb) {
                v8s vf = *(const v8s*)&Vts[(cb * 16 + n) * 144 + ks * 64 + qd * 16];
#pragma unroll
                for (int g = 0; g < 2; ++g)
                    oacc[g][cb] = __builtin_amdgcn_mfma_f32_16x16x32_bf16(vf, pf[g], oacc[g][cb], 0, 0, 0);
            }
        }
    }

    // ---- epilogue
    if (SPLITS == 1) {
#pragma unroll
        for (int g = 0; g < 2; ++g) {
            const float inv = 1.0f / l_[g];
#pragma unroll
            for (int cb = 0; cb < 4; ++cb)
#pragma unroll
                for (int r = 0; r < 4; ++r) oacc[g][cb][r] *= inv;
        }
    } else {
        if (qd == 0) {
#pragma unroll
            for (int g = 0; g < 2; ++g) {
                const size_t row = (size_t)bh * SEQ + rb * 128 + w * 32 + g * 16 + n;
                ml[((size_t)kq * NROWS + row) * 2 + 0] = m_[g];
                ml[((size_t)kq * NROWS + row) * 2 + 1] = l_[g];
            }
        }
    }
    __syncthreads();
#pragma unroll
    for (int g = 0; g < 2; ++g)
#pragma unroll
        for (int cb = 0; cb < 4; ++cb)
            *(v4f*)&smem[(w * 32 + g * 16 + n) * 272 + cb * 64 + qd * 16] = oacc[g][cb];
    __syncthreads();
    const int r_l = tid >> 1, hf = tid & 1;
    float* dst = (SPLITS == 1)
        ? &out[((size_t)bh * SEQ + rb * 128 + r_l) * DH + hf * 32]
        : &Opart[((size_t)kq * NROWS + (size_t)bh * SEQ + rb * 128 + r_l) * DH + hf * 32];
#pragma unroll
    for (int i = 0; i < 8; ++i) {
        float4 t4 = *(const float4*)&smem[r_l * 272 + hf * 128 + i * 16];
        *(float4*)&dst[i * 4] = t4;
    }
}

// ---------------------------------------------------------------------------
// Combine split-K partials.
// ---------------------------------------------------------------------------
__global__ __launch_bounds__(256) void combine_kernel(
    const float* __restrict__ Opart, const float* __restrict__ ml,
    float* __restrict__ out, int splits)
{
    const int tid = threadIdx.x;
    const size_t row = (size_t)blockIdx.x * 16 + (tid >> 4);
    const int d4 = (tid & 15) * 4;
    float M = -1e30f;
    for (int s = 0; s < splits; ++s)
        M = fmaxf(M, ml[((size_t)s * NROWS + row) * 2]);
    float denom = 0.f;
    float4 o = make_float4(0.f, 0.f, 0.f, 0.f);
    for (int s = 0; s < splits; ++s) {
        const float ws = __expf(ml[((size_t)s * NROWS + row) * 2] - M);
        denom += ws * ml[((size_t)s * NROWS + row) * 2 + 1];
        float4 p = *(const float4*)&Opart[((size_t)s * NROWS + row) * DH + d4];
        o.x += ws * p.x; o.y += ws * p.y; o.z += ws * p.z; o.w += ws * p.w;
    }
    const float inv = 1.0f / denom;
    o.x *= inv; o.y *= inv; o.z *= inv; o.w *= inv;
    *(float4*)&out[row * DH + d4] = o;
}

extern "C" void kernel_launch(void* const* d_in, const int* in_sizes, int n_in,
                              void* d_out, int out_size, void* d_ws, size_t ws_size,
                              hipStream_t stream) {
    const float* q    = (const float*)d_in[0];
    const float* k    = (const float*)d_in[1];
    const float* v    = (const float*)d_in[2];
    const float* mask = (const float*)d_in[3];
    const float* Wq   = (const float*)d_in[4];
    const float* bq   = (const float*)d_in[5];
    const float* Wk   = (const float*)d_in[6];
    const float* bk   = (const float*)d_in[7];
    const float* Wv   = (const float*)d_in[8];
    const float* bv   = (const float*)d_in[9];

    unsigned short* Qbf = (unsigned short*)d_ws;                   // 4 MB
    unsigned short* Kbf = Qbf + (size_t)MROWS * EMB;               // 4 MB
    unsigned short* Vbf = Kbf + (size_t)MROWS * EMB;               // 4 MB
    unsigned short* VtG = Vbf + (size_t)MROWS * EMB;               // 4 MB
    float* Opart = (float*)(VtG + (size_t)MROWS * EMB);            // 32 MB
    float* mlp   = Opart + (size_t)4 * NROWS * DH;                 // 1 MB

    const size_t need_split = (size_t)16 * 1024 * 1024
                            + (size_t)4 * NROWS * DH * 4
                            + (size_t)4 * NROWS * 2 * 4;
    const bool do_split = ws_size >= need_split;

    dim3 pgrid(MROWS / 64, EMB / 128, 3);    // 64 x 4 x 3 = 768 blocks
    proj_kernel<<<pgrid, 256, 0, stream>>>(q, k, v, Wq, bq, Wk, bk, Wv, bv,
                                           Qbf, Kbf, Vbf);

    dim3 tgrid(16, SEQ / 128);
    vtrans_kernel<<<tgrid, 256, 0, stream>>>(Vbf, VtG);

    if (do_split) {
        dim3 agrid(16, SEQ / 128, 4);        // 1024 blocks -> 4 blocks/CU
        attn_kernel<4><<<agrid, 256, 0, stream>>>(Qbf, Kbf, VtG, mask,
                                                  Opart, mlp, (float*)d_out);
        combine_kernel<<<NROWS / 16, 256, 0, stream>>>(Opart, mlp, (float*)d_out, 4);
    } else {
        dim3 agrid(16, SEQ / 128, 1);
        attn_kernel<1><<<agrid, 256, 0, stream>>>(Qbf, Kbf, VtG, mask,
                                                  Opart, mlp, (float*)d_out);
    }
}

// Round 7
// 235.213 us; speedup vs baseline: 1.2218x; 1.1976x over previous
//
#include <hip/hip_runtime.h>

// MultiHeadAttention B=2,S=2048,E=512,H=8,dh=64 — bf16 MFMA, split-K flash.
// Head mapping (VERIFIED r3): head h of batch b = contiguous [2048][64] span at
// flat offset (b*8+h)*S*64 of the projected [4096][512] tensor.
// R7: model = everything bound by L2-miss-path traffic (~3.4 TB/s effective).
// (1) attn reverted to r4's use-point mask loads (r6 prefetch desynced blocks,
//     FETCH 114->244 MB) + flat-grid XCD swizzle: XCD = rb%8 so each XCD's L2
//     holds a 2 MB mask slice with 16x bh-reuse.
// (2) proj: 64x128 tiles, flat-grid XCD swizzle putting all 4 nb of one (mb,z)
//     on one XCD (A tile fetched ~once, W strip L2-resident).
// Scale quirk: 1/sqrt(s_k) = 1/sqrt(2048).

#define SEQ 2048
#define EMB 512
#define DH  64
#define MROWS 4096
#define NROWS 32768   // 16 heads * 2048 rows of 64

typedef float  v4f __attribute__((ext_vector_type(4)));
typedef short  v8s __attribute__((ext_vector_type(8)));

static __device__ __forceinline__ unsigned int f2bf(float f) {
    unsigned int u = __float_as_uint(f);
    u += 0x7fffu + ((u >> 16) & 1u);       // RNE
    return u >> 16;
}
static __device__ __forceinline__ unsigned int pack2(float a, float b) {
    return f2bf(a) | (f2bf(b) << 16);
}

// ---------------------------------------------------------------------------
// Projection: C[m][n] = sum_k A[m][k]*W[n][k] + bias[n], fp32 in, bf16 out.
// 64(m) x 128(n) tile, BK=64. Flat grid of 768; decode so ids {c,c+8,c+16,c+24}
// (same XCD under round-robin %8) are the 4 nb of one (mb,z): A-tile reused
// from XCD L2, W strip (1 MB/z) L2-resident.
// ---------------------------------------------------------------------------
__global__ __launch_bounds__(256, 3) void proj_kernel(
    const float* __restrict__ q, const float* __restrict__ k, const float* __restrict__ v,
    const float* __restrict__ Wq, const float* __restrict__ bq,
    const float* __restrict__ Wk, const float* __restrict__ bk,
    const float* __restrict__ Wv, const float* __restrict__ bv,
    unsigned short* __restrict__ Qbf, unsigned short* __restrict__ Kbf,
    unsigned short* __restrict__ Vbf)
{
    __shared__ __align__(16) char smem[27648];   // As 64x144 (9216) | Ws 128x144 (18432)
    char* As = smem;
    char* Ws = smem + 9216;

    // swizzle decode: win = id/32, pos = id%32, xcd = pos%8, nb = pos/8,
    // unit = win*8 + xcd in 0..191 -> mb = unit%64, z = unit/64.
    const int id  = blockIdx.x;
    const int pos = id & 31;
    const int nb  = pos >> 3;
    const int unit = (id >> 5) * 8 + (pos & 7);
    const int mb = unit & 63;
    const int z  = unit >> 6;

    const float* A    = (z == 0) ? q  : (z == 1) ? k  : v;
    const float* W    = (z == 0) ? Wq : (z == 1) ? Wk : Wv;
    const float* bias = (z == 0) ? bq : (z == 1) ? bk : bv;
    unsigned short* Cg = (z == 0) ? Qbf : (z == 1) ? Kbf : Vbf;

    const int tid  = threadIdx.x;
    const int w    = tid >> 6;
    const int lane = tid & 63;
    const int qd   = lane >> 4;     // quad 0..3
    const int n    = lane & 15;
    const int m0 = mb * 64, n0 = nb * 128;

    const int rA = tid & 63,  qA = (tid >> 6) & 3;  // A: row, quarter (16 floats)
    const int rW = tid & 127, hW = tid >> 7;        // W: row, half (32 floats)

    float4 areg[4], wreg[8];
#pragma unroll
    for (int i = 0; i < 4; ++i)
        areg[i] = *(const float4*)&A[(size_t)(m0 + rA) * EMB + qA * 16 + i * 4];
#pragma unroll
    for (int i = 0; i < 8; ++i)
        wreg[i] = *(const float4*)&W[(size_t)(n0 + rW) * EMB + hW * 32 + i * 4];

    v4f acc[8];
#pragma unroll
    for (int cb = 0; cb < 8; ++cb) acc[cb] = (v4f)0.f;

#pragma unroll 1
    for (int kt = 0; kt < 8; ++kt) {
        __syncthreads();
#pragma unroll
        for (int i2 = 0; i2 < 2; ++i2) {
            uint4 pa = { pack2(areg[2*i2].x, areg[2*i2].y), pack2(areg[2*i2].z, areg[2*i2].w),
                         pack2(areg[2*i2+1].x, areg[2*i2+1].y), pack2(areg[2*i2+1].z, areg[2*i2+1].w) };
            *(uint4*)&As[rA * 144 + qA * 32 + i2 * 16] = pa;
        }
#pragma unroll
        for (int i2 = 0; i2 < 4; ++i2) {
            uint4 pw = { pack2(wreg[2*i2].x, wreg[2*i2].y), pack2(wreg[2*i2].z, wreg[2*i2].w),
                         pack2(wreg[2*i2+1].x, wreg[2*i2+1].y), pack2(wreg[2*i2+1].z, wreg[2*i2+1].w) };
            *(uint4*)&Ws[rW * 144 + hW * 64 + i2 * 16] = pw;
        }
        __syncthreads();

        if (kt + 1 < 8) {
#pragma unroll
            for (int i = 0; i < 4; ++i)
                areg[i] = *(const float4*)&A[(size_t)(m0 + rA) * EMB + (kt+1) * 64 + qA * 16 + i * 4];
#pragma unroll
            for (int i = 0; i < 8; ++i)
                wreg[i] = *(const float4*)&W[(size_t)(n0 + rW) * EMB + (kt+1) * 64 + hW * 32 + i * 4];
        }

#pragma unroll
        for (int ks = 0; ks < 2; ++ks) {
            v8s af = *(const v8s*)&As[(w * 16 + n) * 144 + ks * 64 + qd * 16];
#pragma unroll
            for (int cb = 0; cb < 8; ++cb) {
                v8s bfr = *(const v8s*)&Ws[(cb * 16 + n) * 144 + ks * 64 + qd * 16];
                acc[cb] = __builtin_amdgcn_mfma_f32_16x16x32_bf16(af, bfr, acc[cb], 0, 0, 0);
            }
        }
    }

    float bb[8];
#pragma unroll
    for (int cb = 0; cb < 8; ++cb) bb[cb] = bias[n0 + cb * 16 + n];
#pragma unroll
    for (int cb = 0; cb < 8; ++cb)
#pragma unroll
        for (int r = 0; r < 4; ++r) acc[cb][r] += bb[cb];

    __syncthreads();
    // bounce: Ct[64 rows][136 shorts pitch (272B)], then coalesced uint4 stores
    short* Ct = (short*)smem;
#pragma unroll
    for (int cb = 0; cb < 8; ++cb)
#pragma unroll
        for (int r = 0; r < 4; ++r)
            Ct[(w * 16 + qd * 4 + r) * 136 + cb * 16 + n] = (short)f2bf(acc[cb][r]);
    __syncthreads();
    const int rr = tid >> 2, q4 = tid & 3;
#pragma unroll
    for (int i = 0; i < 4; ++i) {
        uint4 t4 = *(const uint4*)&smem[rr * 272 + q4 * 64 + i * 16];
        *(uint4*)&Cg[(size_t)(m0 + rr) * EMB + n0 + q4 * 32 + i * 8] = t4;
    }
}

// ---------------------------------------------------------------------------
// V transpose per head: contiguous [2048][64] head block -> VtG[bh][64][2048].
// ---------------------------------------------------------------------------
__global__ __launch_bounds__(256) void vtrans_kernel(
    const unsigned short* __restrict__ Vbf, unsigned short* __restrict__ VtG)
{
    __shared__ unsigned short T[64 * 136];
    const int bh = blockIdx.x, st = blockIdx.y;
    const int tid = threadIdx.x;
    const unsigned short* Vh = Vbf + (size_t)bh * (SEQ * DH) + (size_t)st * 128 * DH;
#pragma unroll
    for (int it = 0; it < 4; ++it) {
        int c = tid + it * 256;
        int s_l = c >> 3, ch = c & 7;
        uint4 t4 = *(const uint4*)&Vh[(size_t)s_l * DH + ch * 8];
        const unsigned short* e = (const unsigned short*)&t4;
#pragma unroll
        for (int j = 0; j < 8; ++j)
            T[(ch * 8 + j) * 136 + s_l] = e[j];
    }
    __syncthreads();
    const int d = tid >> 2, sq = tid & 3;
    unsigned short* Od = VtG + (size_t)bh * (DH * SEQ) + (size_t)d * SEQ + st * 128;
#pragma unroll
    for (int i = 0; i < 4; ++i) {
        uint4 t4 = *(const uint4*)&T[d * 136 + sq * 32 + i * 8];
        *(uint4*)&Od[sq * 32 + i * 8] = t4;
    }
}

// ---------------------------------------------------------------------------
// Flash attention, bf16 MFMA, transposed scores, split-K. r4 inner loop
// (use-point fp32 mask loads). Flat grid, decoded so XCD = rb%8:
// id = ((kq*16 + bh)*2 + rb_hi)*8 + rb_lo, rb = rb_hi*8 + rb_lo.
// ---------------------------------------------------------------------------
template <int SPLITS>
__global__ __launch_bounds__(256, 4) void attn_kernel(
    const unsigned short* __restrict__ Qbf, const unsigned short* __restrict__ Kbf,
    const unsigned short* __restrict__ VtG, const float* __restrict__ mask,
    float* __restrict__ Opart, float* __restrict__ ml, float* __restrict__ out)
{
    __shared__ __align__(16) char smem[36864];  // Ks 64x144 | Vts 64x144 | Ps 4x(32x144)
    char* Ks  = smem;
    char* Vts = smem + 9216;

    const int tid  = threadIdx.x;
    const int w    = tid >> 6;
    const int lane = tid & 63;
    const int qd   = lane >> 4;
    const int n    = lane & 15;
    char* Ps = smem + 18432 + w * 4608;

    // swizzle decode
    const int id = blockIdx.x;
    const int rb = ((id >> 3) & 1) * 8 + (id & 7);   // rb_hi*8 + rb_lo
    const int bh = (id >> 4) & 15;
    const int kq = id >> 8;                           // 0 when SPLITS==1
    const int KT0 = kq * (32 / SPLITS), KT1 = KT0 + 32 / SPLITS;

    const unsigned short* Qh = Qbf + (size_t)bh * (SEQ * DH);
    const unsigned short* Kh = Kbf + (size_t)bh * (SEQ * DH);
    const unsigned short* Vth = VtG + (size_t)bh * (DH * SEQ);

    const float scale = 0.02209708691207961f;   // 1/sqrt(2048)

    v8s qf[2][2];
#pragma unroll
    for (int g = 0; g < 2; ++g) {
        const size_t qrow = (size_t)(rb * 128 + w * 32 + g * 16 + n);
#pragma unroll
        for (int ks = 0; ks < 2; ++ks)
            qf[g][ks] = *(const v8s*)&Qh[qrow * DH + ks * 32 + qd * 8];
    }

    const int sr = lane;
    uint4 kreg[2], vreg[2];
#pragma unroll
    for (int p = 0; p < 2; ++p) {
        kreg[p] = *(const uint4*)&Kh[(size_t)(KT0 * 64 + sr) * DH + (w * 2 + p) * 8];
        vreg[p] = *(const uint4*)&Vth[(size_t)sr * SEQ + KT0 * 64 + (w * 2 + p) * 8];
    }

    float m_[2] = { -1e30f, -1e30f }, l_[2] = { 0.f, 0.f };
    v4f oacc[2][4];
#pragma unroll
    for (int g = 0; g < 2; ++g)
#pragma unroll
        for (int cb = 0; cb < 4; ++cb) oacc[g][cb] = (v4f)0.f;

#pragma unroll 1
    for (int kt = KT0; kt < KT1; ++kt) {
        __syncthreads();
#pragma unroll
        for (int p = 0; p < 2; ++p) {
            *(uint4*)&Ks [sr * 144 + (w * 2 + p) * 16] = kreg[p];
            *(uint4*)&Vts[sr * 144 + (w * 2 + p) * 16] = vreg[p];
        }
        __syncthreads();

        if (kt + 1 < KT1) {
#pragma unroll
            for (int p = 0; p < 2; ++p) {
                kreg[p] = *(const uint4*)&Kh[(size_t)((kt + 1) * 64 + sr) * DH + (w * 2 + p) * 8];
                vreg[p] = *(const uint4*)&Vth[(size_t)sr * SEQ + (kt + 1) * 64 + (w * 2 + p) * 8];
            }
        }

        // mask loads at use point (r4-verified: keeps co-resident blocks in
        // sync on shared mask lines -> L2 serves the bh-duplicates)
        float4 mk[2][4];
#pragma unroll
        for (int g = 0; g < 2; ++g) {
            const size_t mrow = (size_t)(rb * 128 + w * 32 + g * 16 + n);
#pragma unroll
            for (int cb = 0; cb < 4; ++cb)
                mk[g][cb] = *(const float4*)&mask[mrow * SEQ + kt * 64 + cb * 16 + qd * 4];
        }

        // ---- scores: S^T[s_k][qrow]
        v4f sacc[2][4];
#pragma unroll
        for (int g = 0; g < 2; ++g)
#pragma unroll
            for (int cb = 0; cb < 4; ++cb) sacc[g][cb] = (v4f)0.f;
#pragma unroll
        for (int ks = 0; ks < 2; ++ks)
#pragma unroll
            for (int cb = 0; cb < 4; ++cb) {
                v8s kf = *(const v8s*)&Ks[(cb * 16 + n) * 144 + ks * 64 + qd * 16];
#pragma unroll
                for (int g = 0; g < 2; ++g)
                    sacc[g][cb] = __builtin_amdgcn_mfma_f32_16x16x32_bf16(kf, qf[g][ks], sacc[g][cb], 0, 0, 0);
            }

        // ---- online softmax per qgroup (qrow = lane&15 -> per-lane scalars)
#pragma unroll
        for (int g = 0; g < 2; ++g) {
            float sv[4][4];
            float mx = -1e30f;
#pragma unroll
            for (int cb = 0; cb < 4; ++cb)
#pragma unroll
                for (int r = 0; r < 4; ++r) {
                    float s = fmaf(sacc[g][cb][r], scale, ((const float*)&mk[g][cb])[r]);
                    sv[cb][r] = s;
                    mx = fmaxf(mx, s);
                }
            mx = fmaxf(mx, __shfl_xor(mx, 16));
            mx = fmaxf(mx, __shfl_xor(mx, 32));
            const float mnew  = fmaxf(m_[g], mx);
            const float alpha = __expf(m_[g] - mnew);
            float rs = 0.f;
            float pv[4][4];
#pragma unroll
            for (int cb = 0; cb < 4; ++cb)
#pragma unroll
                for (int r = 0; r < 4; ++r) {
                    float e = __expf(sv[cb][r] - mnew);
                    pv[cb][r] = e;
                    rs += e;
                }
            rs += __shfl_xor(rs, 16);
            rs += __shfl_xor(rs, 32);
            l_[g] = l_[g] * alpha + rs;
            m_[g] = mnew;
#pragma unroll
            for (int cb = 0; cb < 4; ++cb) {
#pragma unroll
                for (int r = 0; r < 4; ++r) oacc[g][cb][r] *= alpha;
                uint2 pk = { pack2(pv[cb][0], pv[cb][1]), pack2(pv[cb][2], pv[cb][3]) };
                *(uint2*)&Ps[(g * 16 + n) * 144 + cb * 32 + qd * 8] = pk;
            }
        }

        // ---- PV: O^T[d][qrow] += Vt * P^T
#pragma unroll
        for (int ks = 0; ks < 2; ++ks) {
            v8s pf[2];
#pragma unroll
            for (int g = 0; g < 2; ++g)
                pf[g] = *(const v8s*)&Ps[(g * 16 + n) * 144 + ks * 64 + qd * 16];
#pragma unroll
            for (int cb = 0; cb < 4; ++cb) {
                v8s vf = *(const v8s*)&Vts[(cb * 16 + n) * 144 + ks * 64 + qd * 16];
#pragma unroll
                for (int g = 0; g < 2; ++g)
                    oacc[g][cb] = __builtin_amdgcn_mfma_f32_16x16x32_bf16(vf, pf[g], oacc[g][cb], 0, 0, 0);
            }
        }
    }

    // ---- epilogue
    if (SPLITS == 1) {
#pragma unroll
        for (int g = 0; g < 2; ++g) {
            const float inv = 1.0f / l_[g];
#pragma unroll
            for (int cb = 0; cb < 4; ++cb)
#pragma unroll
                for (int r = 0; r < 4; ++r) oacc[g][cb][r] *= inv;
        }
    } else {
        if (qd == 0) {
#pragma unroll
            for (int g = 0; g < 2; ++g) {
                const size_t row = (size_t)bh * SEQ + rb * 128 + w * 32 + g * 16 + n;
                ml[((size_t)kq * NROWS + row) * 2 + 0] = m_[g];
                ml[((size_t)kq * NROWS + row) * 2 + 1] = l_[g];
            }
        }
    }
    __syncthreads();
#pragma unroll
    for (int g = 0; g < 2; ++g)
#pragma unroll
        for (int cb = 0; cb < 4; ++cb)
            *(v4f*)&smem[(w * 32 + g * 16 + n) * 272 + cb * 64 + qd * 16] = oacc[g][cb];
    __syncthreads();
    const int r_l = tid >> 1, hf = tid & 1;
    float* dst = (SPLITS == 1)
        ? &out[((size_t)bh * SEQ + rb * 128 + r_l) * DH + hf * 32]
        : &Opart[((size_t)kq * NROWS + (size_t)bh * SEQ + rb * 128 + r_l) * DH + hf * 32];
#pragma unroll
    for (int i = 0; i < 8; ++i) {
        float4 t4 = *(const float4*)&smem[r_l * 272 + hf * 128 + i * 16];
        *(float4*)&dst[i * 4] = t4;
    }
}

// ---------------------------------------------------------------------------
// Combine split-K partials.
// ---------------------------------------------------------------------------
__global__ __launch_bounds__(256) void combine_kernel(
    const float* __restrict__ Opart, const float* __restrict__ ml,
    float* __restrict__ out, int splits)
{
    const int tid = threadIdx.x;
    const size_t row = (size_t)blockIdx.x * 16 + (tid >> 4);
    const int d4 = (tid & 15) * 4;
    float M = -1e30f;
    for (int s = 0; s < splits; ++s)
        M = fmaxf(M, ml[((size_t)s * NROWS + row) * 2]);
    float denom = 0.f;
    float4 o = make_float4(0.f, 0.f, 0.f, 0.f);
    for (int s = 0; s < splits; ++s) {
        const float ws = __expf(ml[((size_t)s * NROWS + row) * 2] - M);
        denom += ws * ml[((size_t)s * NROWS + row) * 2 + 1];
        float4 p = *(const float4*)&Opart[((size_t)s * NROWS + row) * DH + d4];
        o.x += ws * p.x; o.y += ws * p.y; o.z += ws * p.z; o.w += ws * p.w;
    }
    const float inv = 1.0f / denom;
    o.x *= inv; o.y *= inv; o.z *= inv; o.w *= inv;
    *(float4*)&out[row * DH + d4] = o;
}

extern "C" void kernel_launch(void* const* d_in, const int* in_sizes, int n_in,
                              void* d_out, int out_size, void* d_ws, size_t ws_size,
                              hipStream_t stream) {
    const float* q    = (const float*)d_in[0];
    const float* k    = (const float*)d_in[1];
    const float* v    = (const float*)d_in[2];
    const float* mask = (const float*)d_in[3];
    const float* Wq   = (const float*)d_in[4];
    const float* bq   = (const float*)d_in[5];
    const float* Wk   = (const float*)d_in[6];
    const float* bk   = (const float*)d_in[7];
    const float* Wv   = (const float*)d_in[8];
    const float* bv   = (const float*)d_in[9];

    unsigned short* Qbf = (unsigned short*)d_ws;                   // 4 MB
    unsigned short* Kbf = Qbf + (size_t)MROWS * EMB;               // 4 MB
    unsigned short* Vbf = Kbf + (size_t)MROWS * EMB;               // 4 MB
    unsigned short* VtG = Vbf + (size_t)MROWS * EMB;               // 4 MB
    float* Opart = (float*)(VtG + (size_t)MROWS * EMB);            // 32 MB
    float* mlp   = Opart + (size_t)4 * NROWS * DH;                 // 1 MB

    const size_t need_split = (size_t)16 * 1024 * 1024
                            + (size_t)4 * NROWS * DH * 4
                            + (size_t)4 * NROWS * 2 * 4;
    const bool do_split = ws_size >= need_split;

    proj_kernel<<<768, 256, 0, stream>>>(q, k, v, Wq, bq, Wk, bk, Wv, bv,
                                         Qbf, Kbf, Vbf);

    dim3 tgrid(16, SEQ / 128);
    vtrans_kernel<<<tgrid, 256, 0, stream>>>(Vbf, VtG);

    if (do_split) {
        attn_kernel<4><<<1024, 256, 0, stream>>>(Qbf, Kbf, VtG, mask,
                                                 Opart, mlp, (float*)d_out);
        combine_kernel<<<NROWS / 16, 256, 0, stream>>>(Opart, mlp, (float*)d_out, 4);
    } else {
        attn_kernel<1><<<256, 256, 0, stream>>>(Qbf, Kbf, VtG, mask,
                                                Opart, mlp, (float*)d_out);
    }
}

// Round 9
// 187.973 us; speedup vs baseline: 1.5288x; 1.2513x over previous
//
#include <hip/hip_runtime.h>

// MultiHeadAttention B=2,S=2048,E=512,H=8,dh=64 — bf16 MFMA, split-K flash.
// Head mapping (VERIFIED r3): head h of batch b = contiguous [2048][64] span at
// flat offset (b*8+h)*S*64 of the projected [4096][512] tensor.
// R8/R9 theory: phases were bound by per-instruction cache-line touches (gather
// staging: 64 lines/instr). All hot loads made DENSE:
//   - K tile staged contiguously (it is naturally one 8 KB span)
//   - V pre-tiled by vtrans into VtT[bh][kt][d][64] (contiguous 8 KB tiles)
//   - mask pre-tiled ONCE to bf16 in ws, in exact MFMA-fragment order
//   - proj A/W staging re-indexed dense + ds_write_b64
// Opart stored fp16 (error ~3e-5). R9 = R8 with the cvt_pkrtz type fixed
// (__fp16 vector, not _Float16). Scale quirk: 1/sqrt(s_k)=1/sqrt(2048).

#define SEQ 2048
#define EMB 512
#define DH  64
#define MROWS 4096
#define NROWS 32768   // 16 heads * 2048 rows

typedef float  v4f __attribute__((ext_vector_type(4)));
typedef short  v8s __attribute__((ext_vector_type(8)));
typedef __fp16 v2h __attribute__((ext_vector_type(2)));

static __device__ __forceinline__ unsigned int f2bf(float f) {
    unsigned int u = __float_as_uint(f);
    u += 0x7fffu + ((u >> 16) & 1u);       // RNE
    return u >> 16;
}
static __device__ __forceinline__ unsigned int pack2(float a, float b) {
    return f2bf(a) | (f2bf(b) << 16);
}
static __device__ __forceinline__ unsigned int packh2(float a, float b) {
    v2h h = __builtin_amdgcn_cvt_pkrtz(a, b);
    return __builtin_bit_cast(unsigned int, h);
}

// ---------------------------------------------------------------------------
// Projection: C[m][n] = sum_k A[m][k]*W[n][k] + bias[n], fp32 in, bf16 out.
// 64(m) x 128(n), BK=64, XCD swizzle (r7). DENSE staging — thread covers
// contiguous float4 chunks (row = c>>4), packs to bf16, ds_write_b64.
// ---------------------------------------------------------------------------
__global__ __launch_bounds__(256, 3) void proj_kernel(
    const float* __restrict__ q, const float* __restrict__ k, const float* __restrict__ v,
    const float* __restrict__ Wq, const float* __restrict__ bq,
    const float* __restrict__ Wk, const float* __restrict__ bk,
    const float* __restrict__ Wv, const float* __restrict__ bv,
    unsigned short* __restrict__ Qbf, unsigned short* __restrict__ Kbf,
    unsigned short* __restrict__ Vbf)
{
    __shared__ __align__(16) char smem[27648];   // As 64x144 | Ws 128x144
    char* As = smem;
    char* Ws = smem + 9216;

    const int id  = blockIdx.x;
    const int pos = id & 31;
    const int nb  = pos >> 3;
    const int unit = (id >> 5) * 8 + (pos & 7);
    const int mb = unit & 63;
    const int z  = unit >> 6;

    const float* A    = (z == 0) ? q  : (z == 1) ? k  : v;
    const float* W    = (z == 0) ? Wq : (z == 1) ? Wk : Wv;
    const float* bias = (z == 0) ? bq : (z == 1) ? bk : bv;
    unsigned short* Cg = (z == 0) ? Qbf : (z == 1) ? Kbf : Vbf;

    const int tid  = threadIdx.x;
    const int w    = tid >> 6;
    const int lane = tid & 63;
    const int qd   = lane >> 4;
    const int n    = lane & 15;
    const int m0 = mb * 64, n0 = nb * 128;

    float4 areg[4], wreg[8];
#pragma unroll
    for (int i = 0; i < 4; ++i) {
        int c = tid + i * 256;                 // A: 1024 chunks, row=c>>4
        areg[i] = *(const float4*)&A[(size_t)(m0 + (c >> 4)) * EMB + (c & 15) * 4];
    }
#pragma unroll
    for (int i = 0; i < 8; ++i) {
        int c = tid + i * 256;                 // W: 2048 chunks, row=c>>4
        wreg[i] = *(const float4*)&W[(size_t)(n0 + (c >> 4)) * EMB + (c & 15) * 4];
    }

    v4f acc[8];
#pragma unroll
    for (int cb = 0; cb < 8; ++cb) acc[cb] = (v4f)0.f;

#pragma unroll 1
    for (int kt = 0; kt < 8; ++kt) {
        __syncthreads();
#pragma unroll
        for (int i = 0; i < 4; ++i) {
            int c = tid + i * 256;
            uint2 pk = { pack2(areg[i].x, areg[i].y), pack2(areg[i].z, areg[i].w) };
            *(uint2*)&As[(c >> 4) * 144 + (c & 15) * 8] = pk;
        }
#pragma unroll
        for (int i = 0; i < 8; ++i) {
            int c = tid + i * 256;
            uint2 pk = { pack2(wreg[i].x, wreg[i].y), pack2(wreg[i].z, wreg[i].w) };
            *(uint2*)&Ws[(c >> 4) * 144 + (c & 15) * 8] = pk;
        }
        __syncthreads();

        if (kt + 1 < 8) {
#pragma unroll
            for (int i = 0; i < 4; ++i) {
                int c = tid + i * 256;
                areg[i] = *(const float4*)&A[(size_t)(m0 + (c >> 4)) * EMB + (kt+1) * 64 + (c & 15) * 4];
            }
#pragma unroll
            for (int i = 0; i < 8; ++i) {
                int c = tid + i * 256;
                wreg[i] = *(const float4*)&W[(size_t)(n0 + (c >> 4)) * EMB + (kt+1) * 64 + (c & 15) * 4];
            }
        }

#pragma unroll
        for (int ks = 0; ks < 2; ++ks) {
            v8s af = *(const v8s*)&As[(w * 16 + n) * 144 + ks * 64 + qd * 16];
#pragma unroll
            for (int cb = 0; cb < 8; ++cb) {
                v8s bfr = *(const v8s*)&Ws[(cb * 16 + n) * 144 + ks * 64 + qd * 16];
                acc[cb] = __builtin_amdgcn_mfma_f32_16x16x32_bf16(af, bfr, acc[cb], 0, 0, 0);
            }
        }
    }

    float bb[8];
#pragma unroll
    for (int cb = 0; cb < 8; ++cb) bb[cb] = bias[n0 + cb * 16 + n];
#pragma unroll
    for (int cb = 0; cb < 8; ++cb)
#pragma unroll
        for (int r = 0; r < 4; ++r) acc[cb][r] += bb[cb];

    __syncthreads();
    short* Ct = (short*)smem;                  // Ct[64 rows][136 pitch]
#pragma unroll
    for (int cb = 0; cb < 8; ++cb)
#pragma unroll
        for (int r = 0; r < 4; ++r)
            Ct[(w * 16 + qd * 4 + r) * 136 + cb * 16 + n] = (short)f2bf(acc[cb][r]);
    __syncthreads();
    const int rr = tid >> 2, q4 = tid & 3;
#pragma unroll
    for (int i = 0; i < 4; ++i) {
        uint4 t4 = *(const uint4*)&smem[rr * 272 + q4 * 64 + i * 16];
        *(uint4*)&Cg[(size_t)(m0 + rr) * EMB + n0 + q4 * 32 + i * 8] = t4;
    }
}

// ---------------------------------------------------------------------------
// V tile-transpose: Vbf head block [2048][64] -> VtT[bh][kt][d][64] bf16
// (each (bh,kt) tile contiguous 8 KB, dense read + dense write). Grid (16,32).
// ---------------------------------------------------------------------------
__global__ __launch_bounds__(256) void vtrans_kernel(
    const unsigned short* __restrict__ Vbf, unsigned short* __restrict__ VtT)
{
    __shared__ unsigned short T[64 * 136];
    const int bh = blockIdx.x, kt = blockIdx.y;
    const int tid = threadIdx.x;
    const unsigned short* Vh = Vbf + (size_t)bh * (SEQ * DH) + (size_t)kt * 64 * DH;
#pragma unroll
    for (int i = 0; i < 2; ++i) {
        int c = tid + i * 256;                 // 512 uint4 chunks, dense
        int s_l = c >> 3, ch = c & 7;
        uint4 t4 = *(const uint4*)&Vh[c * 8];
        const unsigned short* e = (const unsigned short*)&t4;
#pragma unroll
        for (int j = 0; j < 8; ++j)
            T[(ch * 8 + j) * 136 + s_l] = e[j];
    }
    __syncthreads();
    unsigned short* Ot = VtT + ((size_t)bh * 32 + kt) * (64 * 64);
    const int d = tid >> 2, sq = tid & 3;
#pragma unroll
    for (int i = 0; i < 2; ++i) {
        uint4 t4 = *(const uint4*)&T[d * 136 + sq * 16 + i * 8];
        *(uint4*)&Ot[d * 64 + sq * 16 + i * 8] = t4;
    }
}

// ---------------------------------------------------------------------------
// Mask pre-tile (once): mask[2048][2048] fp32 -> maskT bf16 tiles in exact
// MFMA fragment order: uint2 slot s at tile (rb,kt):
//   s = ((w*2+g)*4+cb)*64 + qd*16+n  holds mask[rb*128+w*32+g*16+n]
//                                        [kt*64+cb*16+qd*4 + r], r=0..3.
// Grid (16, 32).
// ---------------------------------------------------------------------------
__global__ __launch_bounds__(256) void maskt_kernel(
    const float* __restrict__ mask, unsigned int* __restrict__ maskT)
{
    const int rb = blockIdx.x, kt = blockIdx.y;
    const int tid = threadIdx.x;
    unsigned int* tile = maskT + ((size_t)rb * 32 + kt) * 4096;  // 2048 uint2
#pragma unroll
    for (int i = 0; i < 8; ++i) {
        int s = tid + i * 256;                 // 0..2047
        int l  = s & 63;
        int cb = (s >> 6) & 3;
        int g  = (s >> 8) & 1;
        int w  = (s >> 9) & 3;
        int qd = l >> 4, n = l & 15;
        const float4 f = *(const float4*)&mask[
            (size_t)(rb * 128 + w * 32 + g * 16 + n) * SEQ + kt * 64 + cb * 16 + qd * 4];
        uint2 pk = { pack2(f.x, f.y), pack2(f.z, f.w) };
        *(uint2*)&tile[(size_t)s * 2] = pk;
    }
}

// ---------------------------------------------------------------------------
// Flash attention, bf16 MFMA, transposed scores, split-K, XCD swizzle (r7).
// Dense K staging (contiguous tile), V from VtT tiles, mask from maskT
// fragment-ordered bf16 tiles (SPLITS>1). Opart stored fp16.
// SPLITS==1 fallback: fp32 row-major mask, fp32 out direct.
// ---------------------------------------------------------------------------
template <int SPLITS>
__global__ __launch_bounds__(256, 4) void attn_kernel(
    const unsigned short* __restrict__ Qbf, const unsigned short* __restrict__ Kbf,
    const unsigned short* __restrict__ VtT,
    const unsigned int* __restrict__ maskT, const float* __restrict__ maskf,
    unsigned short* __restrict__ Opart, float* __restrict__ ml,
    float* __restrict__ out)
{
    __shared__ __align__(16) char smem[36864];  // Ks 64x144 | Vts 64x144 | Ps 4x(32x144)
    char* Ks  = smem;
    char* Vts = smem + 9216;

    const int tid  = threadIdx.x;
    const int w    = tid >> 6;
    const int lane = tid & 63;
    const int qd   = lane >> 4;
    const int n    = lane & 15;
    char* Ps = smem + 18432 + w * 4608;

    const int id = blockIdx.x;
    const int rb = ((id >> 3) & 1) * 8 + (id & 7);
    const int bh = (id >> 4) & 15;
    const int kq = id >> 8;
    const int KT0 = kq * (32 / SPLITS), KT1 = KT0 + 32 / SPLITS;

    const unsigned short* Qh = Qbf + (size_t)bh * (SEQ * DH);
    const unsigned short* Kh = Kbf + (size_t)bh * (SEQ * DH);
    const unsigned short* Vth = VtT + (size_t)bh * 32 * 4096;

    const float scale = 0.02209708691207961f;   // 1/sqrt(2048)

    v8s qf[2][2];
#pragma unroll
    for (int g = 0; g < 2; ++g) {
        const size_t qrow = (size_t)(rb * 128 + w * 32 + g * 16 + n);
#pragma unroll
        for (int ks = 0; ks < 2; ++ks)
            qf[g][ks] = *(const v8s*)&Qh[qrow * DH + ks * 32 + qd * 8];
    }

    // dense staging: thread covers 16B chunks c=tid and c=tid+256 of the
    // contiguous 8 KB tile (row = c>>3, chunk = c&7)
    uint4 kreg[2], vreg[2];
#pragma unroll
    for (int p = 0; p < 2; ++p) {
        int c = tid + p * 256;
        kreg[p] = *(const uint4*)&Kh[(size_t)KT0 * 4096 + c * 8];
        vreg[p] = *(const uint4*)&Vth[(size_t)KT0 * 4096 + c * 8];
    }

    float m_[2] = { -1e30f, -1e30f }, l_[2] = { 0.f, 0.f };
    v4f oacc[2][4];
#pragma unroll
    for (int g = 0; g < 2; ++g)
#pragma unroll
        for (int cb = 0; cb < 4; ++cb) oacc[g][cb] = (v4f)0.f;

#pragma unroll 1
    for (int kt = KT0; kt < KT1; ++kt) {
        __syncthreads();
#pragma unroll
        for (int p = 0; p < 2; ++p) {
            int c = tid + p * 256;
            *(uint4*)&Ks [(c >> 3) * 144 + (c & 7) * 16] = kreg[p];
            *(uint4*)&Vts[(c >> 3) * 144 + (c & 7) * 16] = vreg[p];
        }
        __syncthreads();

        if (kt + 1 < KT1) {
#pragma unroll
            for (int p = 0; p < 2; ++p) {
                int c = tid + p * 256;
                kreg[p] = *(const uint4*)&Kh[(size_t)(kt + 1) * 4096 + c * 8];
                vreg[p] = *(const uint4*)&Vth[(size_t)(kt + 1) * 4096 + c * 8];
            }
        }

        // mask: dense fragment-ordered uint2 loads (split path)
        uint2 mtu[2][4];
        float4 mk[2][4];
        if (SPLITS > 1) {
            const unsigned int* tile = maskT + ((size_t)rb * 32 + kt) * 4096;
#pragma unroll
            for (int g = 0; g < 2; ++g)
#pragma unroll
                for (int cb = 0; cb < 4; ++cb)
                    mtu[g][cb] = *(const uint2*)&tile[
                        (size_t)((((w * 2 + g) * 4 + cb) * 64) + qd * 16 + n) * 2];
        } else {
#pragma unroll
            for (int g = 0; g < 2; ++g) {
                const size_t mrow = (size_t)(rb * 128 + w * 32 + g * 16 + n);
#pragma unroll
                for (int cb = 0; cb < 4; ++cb)
                    mk[g][cb] = *(const float4*)&maskf[mrow * SEQ + kt * 64 + cb * 16 + qd * 4];
            }
        }

        // ---- scores: S^T[s_k][qrow]
        v4f sacc[2][4];
#pragma unroll
        for (int g = 0; g < 2; ++g)
#pragma unroll
            for (int cb = 0; cb < 4; ++cb) sacc[g][cb] = (v4f)0.f;
#pragma unroll
        for (int ks = 0; ks < 2; ++ks)
#pragma unroll
            for (int cb = 0; cb < 4; ++cb) {
                v8s kf = *(const v8s*)&Ks[(cb * 16 + n) * 144 + ks * 64 + qd * 16];
#pragma unroll
                for (int g = 0; g < 2; ++g)
                    sacc[g][cb] = __builtin_amdgcn_mfma_f32_16x16x32_bf16(kf, qf[g][ks], sacc[g][cb], 0, 0, 0);
            }

        // ---- online softmax
#pragma unroll
        for (int g = 0; g < 2; ++g) {
            float sv[4][4];
            float mx = -1e30f;
#pragma unroll
            for (int cb = 0; cb < 4; ++cb) {
                float mv[4];
                if (SPLITS > 1) {
                    uint2 mu = mtu[g][cb];
                    mv[0] = __uint_as_float(mu.x << 16);
                    mv[1] = __uint_as_float(mu.x & 0xFFFF0000u);
                    mv[2] = __uint_as_float(mu.y << 16);
                    mv[3] = __uint_as_float(mu.y & 0xFFFF0000u);
                } else {
                    mv[0] = mk[g][cb].x; mv[1] = mk[g][cb].y;
                    mv[2] = mk[g][cb].z; mv[3] = mk[g][cb].w;
                }
#pragma unroll
                for (int r = 0; r < 4; ++r) {
                    float s = fmaf(sacc[g][cb][r], scale, mv[r]);
                    sv[cb][r] = s;
                    mx = fmaxf(mx, s);
                }
            }
            mx = fmaxf(mx, __shfl_xor(mx, 16));
            mx = fmaxf(mx, __shfl_xor(mx, 32));
            const float mnew  = fmaxf(m_[g], mx);
            const float alpha = __expf(m_[g] - mnew);
            float rs = 0.f;
            float pv[4][4];
#pragma unroll
            for (int cb = 0; cb < 4; ++cb)
#pragma unroll
                for (int r = 0; r < 4; ++r) {
                    float e = __expf(sv[cb][r] - mnew);
                    pv[cb][r] = e;
                    rs += e;
                }
            rs += __shfl_xor(rs, 16);
            rs += __shfl_xor(rs, 32);
            l_[g] = l_[g] * alpha + rs;
            m_[g] = mnew;
#pragma unroll
            for (int cb = 0; cb < 4; ++cb) {
#pragma unroll
                for (int r = 0; r < 4; ++r) oacc[g][cb][r] *= alpha;
                uint2 pk = { pack2(pv[cb][0], pv[cb][1]), pack2(pv[cb][2], pv[cb][3]) };
                *(uint2*)&Ps[(g * 16 + n) * 144 + cb * 32 + qd * 8] = pk;
            }
        }

        // ---- PV: O^T[d][qrow] += Vt * P^T
#pragma unroll
        for (int ks = 0; ks < 2; ++ks) {
            v8s pf[2];
#pragma unroll
            for (int g = 0; g < 2; ++g)
                pf[g] = *(const v8s*)&Ps[(g * 16 + n) * 144 + ks * 64 + qd * 16];
#pragma unroll
            for (int cb = 0; cb < 4; ++cb) {
                v8s vf = *(const v8s*)&Vts[(cb * 16 + n) * 144 + ks * 64 + qd * 16];
#pragma unroll
                for (int g = 0; g < 2; ++g)
                    oacc[g][cb] = __builtin_amdgcn_mfma_f32_16x16x32_bf16(vf, pf[g], oacc[g][cb], 0, 0, 0);
            }
        }
    }

    // ---- epilogue
    if (SPLITS == 1) {
#pragma unroll
        for (int g = 0; g < 2; ++g) {
            const float inv = 1.0f / l_[g];
#pragma unroll
            for (int cb = 0; cb < 4; ++cb)
#pragma unroll
                for (int r = 0; r < 4; ++r) oacc[g][cb][r] *= inv;
        }
    } else {
        if (qd == 0) {
#pragma unroll
            for (int g = 0; g < 2; ++g) {
                const size_t row = (size_t)bh * SEQ + rb * 128 + w * 32 + g * 16 + n;
                ml[((size_t)kq * NROWS + row) * 2 + 0] = m_[g];
                ml[((size_t)kq * NROWS + row) * 2 + 1] = l_[g];
            }
        }
    }
    __syncthreads();
#pragma unroll
    for (int g = 0; g < 2; ++g)
#pragma unroll
        for (int cb = 0; cb < 4; ++cb)
            *(v4f*)&smem[(w * 32 + g * 16 + n) * 272 + cb * 64 + qd * 16] = oacc[g][cb];
    __syncthreads();
    const int r_l = tid >> 1, hf = tid & 1;
    if (SPLITS == 1) {
        float* dst = &out[((size_t)bh * SEQ + rb * 128 + r_l) * DH + hf * 32];
#pragma unroll
        for (int i = 0; i < 8; ++i) {
            float4 t4 = *(const float4*)&smem[r_l * 272 + hf * 128 + i * 16];
            *(float4*)&dst[i * 4] = t4;
        }
    } else {
        unsigned short* dst = &Opart[((size_t)kq * NROWS + (size_t)bh * SEQ + rb * 128 + r_l) * DH + hf * 32];
#pragma unroll
        for (int i = 0; i < 4; ++i) {
            float4 f0 = *(const float4*)&smem[r_l * 272 + hf * 128 + i * 32];
            float4 f1 = *(const float4*)&smem[r_l * 272 + hf * 128 + i * 32 + 16];
            uint4 o = { packh2(f0.x, f0.y), packh2(f0.z, f0.w),
                        packh2(f1.x, f1.y), packh2(f1.z, f1.w) };
            *(uint4*)&dst[i * 8] = o;
        }
    }
}

// ---------------------------------------------------------------------------
// Combine split-K partials (Opart fp16).
// ---------------------------------------------------------------------------
__global__ __launch_bounds__(256) void combine_kernel(
    const unsigned int* __restrict__ Opart, const float* __restrict__ ml,
    float* __restrict__ out, int splits)
{
    const int tid = threadIdx.x;
    const size_t row = (size_t)blockIdx.x * 16 + (tid >> 4);
    const int d4 = (tid & 15) * 4;             // half index (x4)
    float M = -1e30f;
    for (int s = 0; s < splits; ++s)
        M = fmaxf(M, ml[((size_t)s * NROWS + row) * 2]);
    float denom = 0.f;
    float4 o = make_float4(0.f, 0.f, 0.f, 0.f);
    for (int s = 0; s < splits; ++s) {
        const float ws = __expf(ml[((size_t)s * NROWS + row) * 2] - M);
        denom += ws * ml[((size_t)s * NROWS + row) * 2 + 1];
        uint2 u = *(const uint2*)&Opart[((size_t)s * NROWS + row) * 32 + (d4 >> 1)];
        v2h h0 = __builtin_bit_cast(v2h, u.x);
        v2h h1 = __builtin_bit_cast(v2h, u.y);
        o.x += ws * (float)h0.x; o.y += ws * (float)h0.y;
        o.z += ws * (float)h1.x; o.w += ws * (float)h1.y;
    }
    const float inv = 1.0f / denom;
    o.x *= inv; o.y *= inv; o.z *= inv; o.w *= inv;
    *(float4*)&out[row * DH + d4] = o;
}

extern "C" void kernel_launch(void* const* d_in, const int* in_sizes, int n_in,
                              void* d_out, int out_size, void* d_ws, size_t ws_size,
                              hipStream_t stream) {
    const float* q    = (const float*)d_in[0];
    const float* k    = (const float*)d_in[1];
    const float* v    = (const float*)d_in[2];
    const float* mask = (const float*)d_in[3];
    const float* Wq   = (const float*)d_in[4];
    const float* bq   = (const float*)d_in[5];
    const float* Wk   = (const float*)d_in[6];
    const float* bk   = (const float*)d_in[7];
    const float* Wv   = (const float*)d_in[8];
    const float* bv   = (const float*)d_in[9];

    char* ws = (char*)d_ws;
    const size_t MB = 1024 * 1024;
    unsigned short* Qbf   = (unsigned short*)(ws + 0);         //  0..4  MB
    unsigned short* Kbf   = (unsigned short*)(ws + 4 * MB);    //  4..8  MB
    unsigned short* VtT   = (unsigned short*)(ws + 8 * MB);    //  8..12 MB
    unsigned short* Opart = (unsigned short*)(ws + 12 * MB);   // 12..28 MB (fp16)
    unsigned short* Vbf   = (unsigned short*)(ws + 12 * MB);   // overlay, dead after vtrans
    float*          mlp   = (float*)(ws + 28 * MB);            // 28..29 MB
    unsigned int*   maskT = (unsigned int*)(ws + 29 * MB);     // 29..37 MB

    const size_t need_split = 37 * MB;
    const bool do_split = ws_size >= need_split;

    proj_kernel<<<768, 256, 0, stream>>>(q, k, v, Wq, bq, Wk, bk, Wv, bv,
                                         Qbf, Kbf, Vbf);

    dim3 tgrid(16, 32);
    vtrans_kernel<<<tgrid, 256, 0, stream>>>(Vbf, VtT);

    if (do_split) {
        dim3 mgrid(16, 32);
        maskt_kernel<<<mgrid, 256, 0, stream>>>(mask, maskT);
        attn_kernel<4><<<1024, 256, 0, stream>>>(Qbf, Kbf, VtT, maskT, mask,
                                                 Opart, mlp, (float*)d_out);
        combine_kernel<<<NROWS / 16, 256, 0, stream>>>((const unsigned int*)Opart,
                                                       mlp, (float*)d_out, 4);
    } else {
        attn_kernel<1><<<256, 256, 0, stream>>>(Qbf, Kbf, VtT, maskT, mask,
                                                Opart, mlp, (float*)d_out);
    }
}

// Round 11
// 182.919 us; speedup vs baseline: 1.5711x; 1.0276x over previous
//
#include <hip/hip_runtime.h>

// MultiHeadAttention B=2,S=2048,E=512,H=8,dh=64 — bf16 MFMA, split-K flash.
// Head mapping (VERIFIED r3): flat reinterpretation — head h of batch b is the
// contiguous [2048][64] span at flat offset (b*8+h)*S*64 of the projected
// [4096][512] tensor. NOTE (r10 failure): in (row,col) coords this means
// h = (row&2047)>>8 — row-determined, NOT a column block. Any V transpose must
// go through the flat view (vtrans_kernel does; do not re-derive).
// R11 = r9 structure + verified r10 wins: mask pre-tiled fp32 in MFMA C-layout
// fed as the C operand of the scores MFMA (scale folded into Q); mask pretile
// runs as extra blocks of the proj launch. Separate vtrans (r9-verified).
// Opart fp16 (r9-verified). Scale quirk: 1/sqrt(s_k) = 1/sqrt(2048).

#define SEQ 2048
#define EMB 512
#define DH  64
#define MROWS 4096
#define NROWS 32768   // 16 heads * 2048 rows

typedef float  v4f __attribute__((ext_vector_type(4)));
typedef short  v8s __attribute__((ext_vector_type(8)));
typedef __fp16 v2h __attribute__((ext_vector_type(2)));

static __device__ __forceinline__ unsigned int f2bf(float f) {
    unsigned int u = __float_as_uint(f);
    u += 0x7fffu + ((u >> 16) & 1u);       // RNE
    return u >> 16;
}
static __device__ __forceinline__ unsigned int pack2(float a, float b) {
    return f2bf(a) | (f2bf(b) << 16);
}
static __device__ __forceinline__ unsigned int packh2(float a, float b) {
    v2h h = __builtin_amdgcn_cvt_pkrtz(a, b);
    return __builtin_bit_cast(unsigned int, h);
}

// ---------------------------------------------------------------------------
// Mega kernel: blocks 0..767 = projection (64m x 128n, BK=64, XCD swizzle,
// dense staging — r9-verified, straight bf16 output for all z; z==0 folds
// `scale`); blocks 768..1279 = mask pre-tile to fp32 C-layout tiles.
// ---------------------------------------------------------------------------
__global__ __launch_bounds__(256, 3) void proj_kernel(
    const float* __restrict__ q, const float* __restrict__ k, const float* __restrict__ v,
    const float* __restrict__ Wq, const float* __restrict__ bq,
    const float* __restrict__ Wk, const float* __restrict__ bk,
    const float* __restrict__ Wv, const float* __restrict__ bv,
    const float* __restrict__ mask,
    unsigned short* __restrict__ Qbf, unsigned short* __restrict__ Kbf,
    unsigned short* __restrict__ Vbf, float* __restrict__ maskT)
{
    const int tid = threadIdx.x;

    // ---- mask pre-tile blocks (independent of projection) ----
    if (blockIdx.x >= 768) {
        const int mb2 = blockIdx.x - 768;
        const int rb = mb2 >> 5, kt = mb2 & 31;
        float* tile = maskT + ((size_t)rb * 32 + kt) * 8192;   // 2048 slots x 4 fp32
#pragma unroll
        for (int i = 0; i < 8; ++i) {
            int s = tid + i * 256;             // 0..2047
            int l  = s & 63;
            int cb = (s >> 6) & 3;
            int g  = (s >> 8) & 1;
            int w  = (s >> 9) & 3;
            int qd = l >> 4, n = l & 15;
            float4 f = *(const float4*)&mask[
                (size_t)(rb * 128 + w * 32 + g * 16 + n) * SEQ + kt * 64 + cb * 16 + qd * 4];
            *(float4*)&tile[(size_t)s * 4] = f;
        }
        return;
    }

    __shared__ __align__(16) char smem[27648];   // As 64x144 | Ws 128x144
    char* As = smem;
    char* Ws = smem + 9216;

    const int id  = blockIdx.x;
    const int pos = id & 31;
    const int nb  = pos >> 3;
    const int unit = (id >> 5) * 8 + (pos & 7);
    const int mb = unit & 63;
    const int z  = unit >> 6;

    const float* A    = (z == 0) ? q  : (z == 1) ? k  : v;
    const float* W    = (z == 0) ? Wq : (z == 1) ? Wk : Wv;
    const float* bias = (z == 0) ? bq : (z == 1) ? bk : bv;
    unsigned short* Cg = (z == 0) ? Qbf : (z == 1) ? Kbf : Vbf;

    const int w    = tid >> 6;
    const int lane = tid & 63;
    const int qd   = lane >> 4;
    const int n    = lane & 15;
    const int m0 = mb * 64, n0 = nb * 128;

    float4 areg[4], wreg[8];
#pragma unroll
    for (int i = 0; i < 4; ++i) {
        int c = tid + i * 256;                 // A: 1024 chunks, row=c>>4
        areg[i] = *(const float4*)&A[(size_t)(m0 + (c >> 4)) * EMB + (c & 15) * 4];
    }
#pragma unroll
    for (int i = 0; i < 8; ++i) {
        int c = tid + i * 256;                 // W: 2048 chunks, row=c>>4
        wreg[i] = *(const float4*)&W[(size_t)(n0 + (c >> 4)) * EMB + (c & 15) * 4];
    }

    v4f acc[8];
#pragma unroll
    for (int cb = 0; cb < 8; ++cb) acc[cb] = (v4f)0.f;

#pragma unroll 1
    for (int kt = 0; kt < 8; ++kt) {
        __syncthreads();
#pragma unroll
        for (int i = 0; i < 4; ++i) {
            int c = tid + i * 256;
            uint2 pk = { pack2(areg[i].x, areg[i].y), pack2(areg[i].z, areg[i].w) };
            *(uint2*)&As[(c >> 4) * 144 + (c & 15) * 8] = pk;
        }
#pragma unroll
        for (int i = 0; i < 8; ++i) {
            int c = tid + i * 256;
            uint2 pk = { pack2(wreg[i].x, wreg[i].y), pack2(wreg[i].z, wreg[i].w) };
            *(uint2*)&Ws[(c >> 4) * 144 + (c & 15) * 8] = pk;
        }
        __syncthreads();

        if (kt + 1 < 8) {
#pragma unroll
            for (int i = 0; i < 4; ++i) {
                int c = tid + i * 256;
                areg[i] = *(const float4*)&A[(size_t)(m0 + (c >> 4)) * EMB + (kt+1) * 64 + (c & 15) * 4];
            }
#pragma unroll
            for (int i = 0; i < 8; ++i) {
                int c = tid + i * 256;
                wreg[i] = *(const float4*)&W[(size_t)(n0 + (c >> 4)) * EMB + (kt+1) * 64 + (c & 15) * 4];
            }
        }

#pragma unroll
        for (int ks = 0; ks < 2; ++ks) {
            v8s af = *(const v8s*)&As[(w * 16 + n) * 144 + ks * 64 + qd * 16];
#pragma unroll
            for (int cb = 0; cb < 8; ++cb) {
                v8s bfr = *(const v8s*)&Ws[(cb * 16 + n) * 144 + ks * 64 + qd * 16];
                acc[cb] = __builtin_amdgcn_mfma_f32_16x16x32_bf16(af, bfr, acc[cb], 0, 0, 0);
            }
        }
    }

    const float osc = (z == 0) ? 0.02209708691207961f : 1.0f;  // fold scale into Q
    float bb[8];
#pragma unroll
    for (int cb = 0; cb < 8; ++cb) bb[cb] = bias[n0 + cb * 16 + n];
#pragma unroll
    for (int cb = 0; cb < 8; ++cb)
#pragma unroll
        for (int r = 0; r < 4; ++r) acc[cb][r] = (acc[cb][r] + bb[cb]) * osc;

    __syncthreads();
    short* Ct = (short*)smem;                  // Ct[64 rows][136 pitch]
#pragma unroll
    for (int cb = 0; cb < 8; ++cb)
#pragma unroll
        for (int r = 0; r < 4; ++r)
            Ct[(w * 16 + qd * 4 + r) * 136 + cb * 16 + n] = (short)f2bf(acc[cb][r]);
    __syncthreads();
    const int rr = tid >> 2, q4 = tid & 3;
#pragma unroll
    for (int i = 0; i < 4; ++i) {
        uint4 t4 = *(const uint4*)&smem[rr * 272 + q4 * 64 + i * 16];
        *(uint4*)&Cg[(size_t)(m0 + rr) * EMB + n0 + q4 * 32 + i * 8] = t4;
    }
}

// ---------------------------------------------------------------------------
// V tile-transpose (r9-VERIFIED, do not fuse into proj — head index depends on
// the projected ROW): Vbf flat-viewed head block [2048][64] ->
// VtT[bh][kt][d][64] bf16 (contiguous 8 KB tiles). Grid (16, 32).
// ---------------------------------------------------------------------------
__global__ __launch_bounds__(256) void vtrans_kernel(
    const unsigned short* __restrict__ Vbf, unsigned short* __restrict__ VtT)
{
    __shared__ unsigned short T[64 * 136];
    const int bh = blockIdx.x, kt = blockIdx.y;
    const int tid = threadIdx.x;
    const unsigned short* Vh = Vbf + (size_t)bh * (SEQ * DH) + (size_t)kt * 64 * DH;
#pragma unroll
    for (int i = 0; i < 2; ++i) {
        int c = tid + i * 256;                 // 512 uint4 chunks, dense
        int s_l = c >> 3, ch = c & 7;
        uint4 t4 = *(const uint4*)&Vh[c * 8];
        const unsigned short* e = (const unsigned short*)&t4;
#pragma unroll
        for (int j = 0; j < 8; ++j)
            T[(ch * 8 + j) * 136 + s_l] = e[j];
    }
    __syncthreads();
    unsigned short* Ot = VtT + ((size_t)bh * 32 + kt) * (64 * 64);
    const int d = tid >> 2, sq = tid & 3;
#pragma unroll
    for (int i = 0; i < 2; ++i) {
        uint4 t4 = *(const uint4*)&T[d * 136 + sq * 16 + i * 8];
        *(uint4*)&Ot[d * 64 + sq * 16 + i * 8] = t4;
    }
}

// ---------------------------------------------------------------------------
// Flash attention, bf16 MFMA, transposed scores, split-K, XCD swizzle (r7).
// Mask tile (fp32, C-layout) is the C operand of the scores MFMA chain —
// softmax reads sacc directly (Q carries `scale`). Dense K/V staging (r9).
// SPLITS==1 fallback: raw fp32 mask added in softmax.
// ---------------------------------------------------------------------------
template <int SPLITS>
__global__ __launch_bounds__(256, 4) void attn_kernel(
    const unsigned short* __restrict__ Qbf, const unsigned short* __restrict__ Kbf,
    const unsigned short* __restrict__ VtT,
    const float* __restrict__ maskT, const float* __restrict__ maskf,
    unsigned short* __restrict__ Opart, float* __restrict__ ml,
    float* __restrict__ out)
{
    __shared__ __align__(16) char smem[36864];  // Ks 64x144 | Vts 64x144 | Ps 4x(32x144)
    char* Ks  = smem;
    char* Vts = smem + 9216;

    const int tid  = threadIdx.x;
    const int w    = tid >> 6;
    const int lane = tid & 63;
    const int qd   = lane >> 4;
    const int n    = lane & 15;
    char* Ps = smem + 18432 + w * 4608;

    const int id = blockIdx.x;
    const int rb = ((id >> 3) & 1) * 8 + (id & 7);
    const int bh = (id >> 4) & 15;
    const int kq = id >> 8;
    const int KT0 = kq * (32 / SPLITS), KT1 = KT0 + 32 / SPLITS;

    const unsigned short* Qh = Qbf + (size_t)bh * (SEQ * DH);
    const unsigned short* Kh = Kbf + (size_t)bh * (SEQ * DH);
    const unsigned short* Vth = VtT + (size_t)bh * 32 * 4096;

    v8s qf[2][2];
#pragma unroll
    for (int g = 0; g < 2; ++g) {
        const size_t qrow = (size_t)(rb * 128 + w * 32 + g * 16 + n);
#pragma unroll
        for (int ks = 0; ks < 2; ++ks)
            qf[g][ks] = *(const v8s*)&Qh[qrow * DH + ks * 32 + qd * 8];
    }

    // dense staging: thread covers 16B chunks c=tid, c=tid+256 of the 8 KB tile
    uint4 kreg[2], vreg[2];
#pragma unroll
    for (int p = 0; p < 2; ++p) {
        int c = tid + p * 256;
        kreg[p] = *(const uint4*)&Kh[(size_t)KT0 * 4096 + c * 8];
        vreg[p] = *(const uint4*)&Vth[(size_t)KT0 * 4096 + c * 8];
    }

    float m_[2] = { -1e30f, -1e30f }, l_[2] = { 0.f, 0.f };
    v4f oacc[2][4];
#pragma unroll
    for (int g = 0; g < 2; ++g)
#pragma unroll
        for (int cb = 0; cb < 4; ++cb) oacc[g][cb] = (v4f)0.f;

#pragma unroll 1
    for (int kt = KT0; kt < KT1; ++kt) {
        __syncthreads();
#pragma unroll
        for (int p = 0; p < 2; ++p) {
            int c = tid + p * 256;
            *(uint4*)&Ks [(c >> 3) * 144 + (c & 7) * 16] = kreg[p];
            *(uint4*)&Vts[(c >> 3) * 144 + (c & 7) * 16] = vreg[p];
        }
        __syncthreads();

        // ---- mask tile loads (C operand of the scores MFMA)
        v4f sacc[2][4];
        float4 mk[2][4];
        if (SPLITS > 1) {
            const float* tileF = maskT + ((size_t)rb * 32 + kt) * 8192;
#pragma unroll
            for (int g = 0; g < 2; ++g)
#pragma unroll
                for (int cb = 0; cb < 4; ++cb)
                    sacc[g][cb] = *(const v4f*)&tileF[
                        (size_t)((((w * 2 + g) * 4 + cb) * 64) + qd * 16 + n) * 4];
        } else {
#pragma unroll
            for (int g = 0; g < 2; ++g) {
                const size_t mrow = (size_t)(rb * 128 + w * 32 + g * 16 + n);
#pragma unroll
                for (int cb = 0; cb < 4; ++cb) {
                    mk[g][cb] = *(const float4*)&maskf[mrow * SEQ + kt * 64 + cb * 16 + qd * 4];
                    sacc[g][cb] = (v4f)0.f;
                }
            }
        }

        if (kt + 1 < KT1) {
#pragma unroll
            for (int p = 0; p < 2; ++p) {
                int c = tid + p * 256;
                kreg[p] = *(const uint4*)&Kh[(size_t)(kt + 1) * 4096 + c * 8];
                vreg[p] = *(const uint4*)&Vth[(size_t)(kt + 1) * 4096 + c * 8];
            }
        }

        // ---- scores: S^T[s_k][qrow], accumulated onto the mask tile
#pragma unroll
        for (int ks = 0; ks < 2; ++ks)
#pragma unroll
            for (int cb = 0; cb < 4; ++cb) {
                v8s kf = *(const v8s*)&Ks[(cb * 16 + n) * 144 + ks * 64 + qd * 16];
#pragma unroll
                for (int g = 0; g < 2; ++g)
                    sacc[g][cb] = __builtin_amdgcn_mfma_f32_16x16x32_bf16(kf, qf[g][ks], sacc[g][cb], 0, 0, 0);
            }

        // ---- online softmax (sacc already = scaled scores + mask)
#pragma unroll
        for (int g = 0; g < 2; ++g) {
            float mx = -1e30f;
#pragma unroll
            for (int cb = 0; cb < 4; ++cb) {
                if (SPLITS == 1) {
                    sacc[g][cb][0] += mk[g][cb].x; sacc[g][cb][1] += mk[g][cb].y;
                    sacc[g][cb][2] += mk[g][cb].z; sacc[g][cb][3] += mk[g][cb].w;
                }
#pragma unroll
                for (int r = 0; r < 4; ++r) mx = fmaxf(mx, sacc[g][cb][r]);
            }
            mx = fmaxf(mx, __shfl_xor(mx, 16));
            mx = fmaxf(mx, __shfl_xor(mx, 32));
            const float mnew  = fmaxf(m_[g], mx);
            const float alpha = __expf(m_[g] - mnew);
            float rs = 0.f;
            float pv[4][4];
#pragma unroll
            for (int cb = 0; cb < 4; ++cb)
#pragma unroll
                for (int r = 0; r < 4; ++r) {
                    float e = __expf(sacc[g][cb][r] - mnew);
                    pv[cb][r] = e;
                    rs += e;
                }
            rs += __shfl_xor(rs, 16);
            rs += __shfl_xor(rs, 32);
            l_[g] = l_[g] * alpha + rs;
            m_[g] = mnew;
#pragma unroll
            for (int cb = 0; cb < 4; ++cb) {
#pragma unroll
                for (int r = 0; r < 4; ++r) oacc[g][cb][r] *= alpha;
                uint2 pk = { pack2(pv[cb][0], pv[cb][1]), pack2(pv[cb][2], pv[cb][3]) };
                *(uint2*)&Ps[(g * 16 + n) * 144 + cb * 32 + qd * 8] = pk;
            }
        }

        // ---- PV: O^T[d][qrow] += Vt * P^T
#pragma unroll
        for (int ks = 0; ks < 2; ++ks) {
            v8s pf[2];
#pragma unroll
            for (int g = 0; g < 2; ++g)
                pf[g] = *(const v8s*)&Ps[(g * 16 + n) * 144 + ks * 64 + qd * 16];
#pragma unroll
            for (int cb = 0; cb < 4; ++cb) {
                v8s vf = *(const v8s*)&Vts[(cb * 16 + n) * 144 + ks * 64 + qd * 16];
#pragma unroll
                for (int g = 0; g < 2; ++g)
                    oacc[g][cb] = __builtin_amdgcn_mfma_f32_16x16x32_bf16(vf, pf[g], oacc[g][cb], 0, 0, 0);
            }
        }
    }

    // ---- epilogue
    if (SPLITS == 1) {
#pragma unroll
        for (int g = 0; g < 2; ++g) {
            const float inv = 1.0f / l_[g];
#pragma unroll
            for (int cb = 0; cb < 4; ++cb)
#pragma unroll
                for (int r = 0; r < 4; ++r) oacc[g][cb][r] *= inv;
        }
    } else {
        if (qd == 0) {
#pragma unroll
            for (int g = 0; g < 2; ++g) {
                const size_t row = (size_t)bh * SEQ + rb * 128 + w * 32 + g * 16 + n;
                ml[((size_t)kq * NROWS + row) * 2 + 0] = m_[g];
                ml[((size_t)kq * NROWS + row) * 2 + 1] = l_[g];
            }
        }
    }
    __syncthreads();
#pragma unroll
    for (int g = 0; g < 2; ++g)
#pragma unroll
        for (int cb = 0; cb < 4; ++cb)
            *(v4f*)&smem[(w * 32 + g * 16 + n) * 272 + cb * 64 + qd * 16] = oacc[g][cb];
    __syncthreads();
    const int r_l = tid >> 1, hf = tid & 1;
    if (SPLITS == 1) {
        float* dst = &out[((size_t)bh * SEQ + rb * 128 + r_l) * DH + hf * 32];
#pragma unroll
        for (int i = 0; i < 8; ++i) {
            float4 t4 = *(const float4*)&smem[r_l * 272 + hf * 128 + i * 16];
            *(float4*)&dst[i * 4] = t4;
        }
    } else {
        unsigned short* dst = &Opart[((size_t)kq * NROWS + (size_t)bh * SEQ + rb * 128 + r_l) * DH + hf * 32];
#pragma unroll
        for (int i = 0; i < 4; ++i) {
            float4 f0 = *(const float4*)&smem[r_l * 272 + hf * 128 + i * 32];
            float4 f1 = *(const float4*)&smem[r_l * 272 + hf * 128 + i * 32 + 16];
            uint4 o = { packh2(f0.x, f0.y), packh2(f0.z, f0.w),
                        packh2(f1.x, f1.y), packh2(f1.z, f1.w) };
            *(uint4*)&dst[i * 8] = o;
        }
    }
}

// ---------------------------------------------------------------------------
// Combine split-K partials (Opart fp16).
// ---------------------------------------------------------------------------
__global__ __launch_bounds__(256) void combine_kernel(
    const unsigned int* __restrict__ Opart, const float* __restrict__ ml,
    float* __restrict__ out, int splits)
{
    const int tid = threadIdx.x;
    const size_t row = (size_t)blockIdx.x * 16 + (tid >> 4);
    const int d4 = (tid & 15) * 4;
    float M = -1e30f;
    for (int s = 0; s < splits; ++s)
        M = fmaxf(M, ml[((size_t)s * NROWS + row) * 2]);
    float denom = 0.f;
    float4 o = make_float4(0.f, 0.f, 0.f, 0.f);
    for (int s = 0; s < splits; ++s) {
        const float ws = __expf(ml[((size_t)s * NROWS + row) * 2] - M);
        denom += ws * ml[((size_t)s * NROWS + row) * 2 + 1];
        uint2 u = *(const uint2*)&Opart[((size_t)s * NROWS + row) * 32 + (d4 >> 1)];
        v2h h0 = __builtin_bit_cast(v2h, u.x);
        v2h h1 = __builtin_bit_cast(v2h, u.y);
        o.x += ws * (float)h0.x; o.y += ws * (float)h0.y;
        o.z += ws * (float)h1.x; o.w += ws * (float)h1.y;
    }
    const float inv = 1.0f / denom;
    o.x *= inv; o.y *= inv; o.z *= inv; o.w *= inv;
    *(float4*)&out[row * DH + d4] = o;
}

extern "C" void kernel_launch(void* const* d_in, const int* in_sizes, int n_in,
                              void* d_out, int out_size, void* d_ws, size_t ws_size,
                              hipStream_t stream) {
    const float* q    = (const float*)d_in[0];
    const float* k    = (const float*)d_in[1];
    const float* v    = (const float*)d_in[2];
    const float* mask = (const float*)d_in[3];
    const float* Wq   = (const float*)d_in[4];
    const float* bq   = (const float*)d_in[5];
    const float* Wk   = (const float*)d_in[6];
    const float* bk   = (const float*)d_in[7];
    const float* Wv   = (const float*)d_in[8];
    const float* bv   = (const float*)d_in[9];

    char* ws = (char*)d_ws;
    const size_t MB = 1024 * 1024;
    unsigned short* Qbf   = (unsigned short*)(ws + 0);         //  0..4  MB
    unsigned short* Kbf   = (unsigned short*)(ws + 4 * MB);    //  4..8  MB
    unsigned short* VtT   = (unsigned short*)(ws + 8 * MB);    //  8..12 MB
    unsigned short* Opart = (unsigned short*)(ws + 12 * MB);   // 12..28 MB (fp16)
    unsigned short* Vbf   = (unsigned short*)(ws + 12 * MB);   // overlay, dead after vtrans
    float*          mlp   = (float*)(ws + 28 * MB);            // 28..29 MB
    float*          maskT = (float*)(ws + 29 * MB);            // 29..45 MB (fp32)

    const size_t need_split = 45 * MB;                         // ws >= 49 MB proven (r4)
    const bool do_split = ws_size >= need_split;

    if (do_split) {
        proj_kernel<<<1280, 256, 0, stream>>>(q, k, v, Wq, bq, Wk, bk, Wv, bv,
                                              mask, Qbf, Kbf, Vbf, maskT);
        dim3 tgrid(16, 32);
        vtrans_kernel<<<tgrid, 256, 0, stream>>>(Vbf, VtT);
        attn_kernel<4><<<1024, 256, 0, stream>>>(Qbf, Kbf, VtT, maskT, mask,
                                                 Opart, mlp, (float*)d_out);
        combine_kernel<<<NROWS / 16, 256, 0, stream>>>((const unsigned int*)Opart,
                                                       mlp, (float*)d_out, 4);
    } else {
        proj_kernel<<<768, 256, 0, stream>>>(q, k, v, Wq, bq, Wk, bk, Wv, bv,
                                             mask, Qbf, Kbf, Vbf, maskT);
        dim3 tgrid(16, 32);
        vtrans_kernel<<<tgrid, 256, 0, stream>>>(Vbf, VtT);
        attn_kernel<1><<<256, 256, 0, stream>>>(Qbf, Kbf, VtT, maskT, mask,
                                                Opart, mlp, (float*)d_out);
    }
}